// Round 8
// baseline (615.739 us; speedup 1.0000x reference)
//
#include <hip/hip_runtime.h>
#include <hip/hip_bf16.h>

#define NP1 50176      // 224*224
#define NP2 12544      // 112*112
#define NPP 12996      // 114*114 zero-padded map

typedef __attribute__((ext_vector_type(8))) short short8;   // 8 bf16 = 4 VGPRs
typedef __attribute__((ext_vector_type(4))) float f32x4;

__device__ __forceinline__ unsigned short f2bu(float f){
  __hip_bfloat16 h = __float2bfloat16(f);
  return *reinterpret_cast<unsigned short*>(&h);
}

// ---- workspace layout (float slots) ----
#define S_SUM1   0          // 128
#define S_SUM2   128        // 512
#define S_STATS1 640        // 128
#define S_STATS2 768        // 512
#define S_W2T    1280       // 576*256 = 147456 fp32
#define S_WOFF2  148736     // 2304*32 = 73728 fp32 (k = n*256+c order)
#define S_W4F    222464     // 589824 bf16 -> 294912 slots (frag-ready [kt][oc][kk], k = n*256+c)
#define S_OFFB   517376     // 2*18*112*112 = 451584 fp32 (NCHW)
#define S_PPAD   968960     // 2*64*114*114 = 1663488 fp32 (NCHW padded)
#define S_HPAD   2632448    // 2*114*114*256 = 6653952 fp32 (NHWC padded)
#define WS_NEED_FLOATS 9286400ull
#define WS_NEED_BYTES  (WS_NEED_FLOATS*4ull)

// ---------- weight prep ----------
__global__ void k_w2T(const float* __restrict__ w2, float* __restrict__ w2T){
  int idx = blockIdx.x*256+threadIdx.x;  int kk = idx>>8, oc = idx&255;   // k = c*9+n
  w2T[idx] = w2[oc*576 + kk];
}
// w4 frag-ready bf16: w4f[kt*8192 + oc*32 + kk] = w4[oc][c][n], k = kt*32+kk = n*256+c
__global__ void k_w4f(const float* __restrict__ w4, unsigned short* __restrict__ w4f){
  int idx = blockIdx.x*256+threadIdx.x;        // 589824
  int kt = idx/8192; int r = idx - kt*8192;
  int oc = r>>5, kk = r&31;
  int k = kt*32 + kk; int n = k>>8, c = k&255;
  w4f[idx] = f2bu(w4[oc*2304 + c*9 + n]);
}
// woff2[k][oc], k = n*256+c (matches convoff A-order), oc padded to 32
__global__ void k_woff2(const float* __restrict__ woff, float* __restrict__ woff2){
  int idx = blockIdx.x*256+threadIdx.x;        // 73728
  int k = idx>>5, oc = idx&31;
  int n = k>>8, c = k&255;
  woff2[idx] = (oc<18) ? woff[oc*2304 + c*9 + n] : 0.f;
}

// ---- conv1+bias+ReLU + 2x2 avgpool, LDS x-tile; BN1 partial stats ----
__global__ __launch_bounds__(256) void k_conv1pool(
    const float* __restrict__ x, const float* __restrict__ w1, const float* __restrict__ b1,
    float* __restrict__ ppad, float* __restrict__ sum1){
  __shared__ float xs[3*34*34];         // 13872 B
  int bid = blockIdx.x;                 // 6272 = 2*64*49
  int tile = bid % 49; int oc = (bid/49) & 63; int b = bid/(49*64);
  int tu = tile/7, tv = tile - 7*(tile/7);
  int tid = threadIdx.x;
  int in0 = tu*32 - 1, jn0 = tv*32 - 1;
  for(int t=tid; t<3468; t+=256){
    int c = t/1156; int r2 = t - c*1156; int rr = r2/34; int cc = r2 - rr*34;
    int ii = in0+rr, jj = jn0+cc;
    xs[t] = (ii>=0 && ii<224 && jj>=0 && jj<224) ? x[(size_t)(b*3+c)*NP1 + ii*224+jj] : 0.f;
  }
  float w[27];
  #pragma unroll
  for(int t=0;t<27;t++) w[t] = w1[oc*27+t];
  float bia = b1[oc];
  __syncthreads();
  int u = tid>>4, v = tid&15;           // local pooled coords
  float s1=0.f, s2=0.f, pl=0.f;
  #pragma unroll
  for(int dy=0;dy<2;dy++){
    #pragma unroll
    for(int dx=0;dx<2;dx++){
      float acc = bia;
      #pragma unroll
      for(int c=0;c<3;c++)
        #pragma unroll
        for(int kh=0;kh<3;kh++)
          #pragma unroll
          for(int kw=0;kw<3;kw++)
            acc += xs[c*1156 + (2*u+dy+kh)*34 + (2*v+dx+kw)] * w[c*9+kh*3+kw];
      acc = fmaxf(acc, 0.f);            // relu BEFORE BN
      pl += acc; s1 += acc; s2 += acc*acc;
    }
  }
  int U = tu*16+u, V = tv*16+v;
  ppad[(size_t)(b*64+oc)*NPP + (U+1)*114 + (V+1)] = 0.25f*pl;
  __shared__ float r1[256], r2[256];
  r1[tid]=s1; r2[tid]=s2; __syncthreads();
  for(int o=128;o>0;o>>=1){
    if(tid<o){ r1[tid]+=r1[tid+o]; r2[tid]+=r2[tid+o]; }
    __syncthreads();
  }
  if(tid==0){ atomicAdd(&sum1[oc], r1[0]); atomicAdd(&sum1[64+oc], r2[0]); }
}

__global__ void k_fin1(const float* __restrict__ sum1, const float* __restrict__ g1,
                       const float* __restrict__ be1, float* __restrict__ stats1){
  int ch = threadIdx.x;                 // 64
  float n = 2.f*(float)NP1;
  float mean = sum1[ch]/n;
  float var  = sum1[64+ch]/n - mean*mean;
  float sc = g1[ch]/sqrtf(var + 1e-5f);
  stats1[ch]    = sc;
  stats1[64+ch] = be1[ch] - mean*sc;
}

// ---- in-place BN1 affine on ppad interior; zero border ----
__global__ void k_affine1(float* __restrict__ ppad, const float* __restrict__ stats1){
  int idx = blockIdx.x*256+threadIdx.x;    // 1663488
  int yp = idx % 114; int t = idx/114; int xp = t % 114; t /= 114;
  int c = t & 63;
  bool in = (xp>=1 && xp<=112 && yp>=1 && yp<=112);
  ppad[idx] = in ? (stats1[c]*ppad[idx] + stats1[64+c]) : 0.f;
}

// ---- conv2 GEMM: M=25088,N=256,K=576; bias+relu RAW -> hpad NHWC interior ----
__global__ __launch_bounds__(256) void k_conv2(const float* __restrict__ ppad,
        const float* __restrict__ w2T, const float* __restrict__ b2, float* __restrict__ hpad){
  __shared__ float smem[9216];          // Alds[0,1024) | Blds[1024,9216); tb reuses [0,8224)
  float* Alds = smem; float* Blds = smem+1024; float* tb = smem;
  const int tid = threadIdx.x;
  const int mbase = blockIdx.x*32;
  const int b = mbase/NP2; const int ijbase = mbase - b*NP2;
  const int oc0 = (tid & 31)*8;
  const int p0  = (tid >> 5)*4;
  const float* pb = ppad + (size_t)b*64*NPP;
  float acc[4][8] = {};
  for(int k0=0;k0<576;k0+=32){
    __syncthreads();
    { const float4* src = (const float4*)(w2T + k0*256);
      float4* dst = (float4*)Blds;
      #pragma unroll
      for(int r=0;r<8;r++) dst[r*256+tid] = src[r*256+tid]; }
    #pragma unroll
    for(int r=0;r<4;r++){
      int e = r*256+tid;
      int kk = e>>5, p = e&31;
      int k = k0+kk; int c = k/9; int n = k - 9*c;
      int ij = ijbase+p; int i = ij/112, j = ij - i*112;
      Alds[kk*32+p] = pb[(c*114 + i + n/3)*114 + j + (n%3)];
    }
    __syncthreads();
    #pragma unroll
    for(int kk=0;kk<32;kk++){
      float a0=Alds[kk*32+p0+0], a1=Alds[kk*32+p0+1], a2=Alds[kk*32+p0+2], a3=Alds[kk*32+p0+3];
      const float* bp = &Blds[kk*256+oc0];
      #pragma unroll
      for(int o=0;o<8;o++){
        float bv = bp[o];
        acc[0][o]=fmaf(a0,bv,acc[0][o]); acc[1][o]=fmaf(a1,bv,acc[1][o]);
        acc[2][o]=fmaf(a2,bv,acc[2][o]); acc[3][o]=fmaf(a3,bv,acc[3][o]);
      }
    }
  }
  __syncthreads();
  #pragma unroll
  for(int p=0;p<4;p++)
    #pragma unroll
    for(int o=0;o<8;o++) tb[(p0+p)*257 + oc0+o] = acc[p][o];
  __syncthreads();
  #pragma unroll
  for(int it=0; it<8; it++){
    int id = it*256 + tid;
    int px = id>>6, oc4 = id&63;
    int ij = ijbase+px; int i = ij/112, j = ij - i*112;
    int pp = (i+1)*114 + (j+1);
    float4 v;
    v.x = fmaxf(tb[px*257 + oc4*4+0] + b2[oc4*4+0], 0.f);
    v.y = fmaxf(tb[px*257 + oc4*4+1] + b2[oc4*4+1], 0.f);
    v.z = fmaxf(tb[px*257 + oc4*4+2] + b2[oc4*4+2], 0.f);
    v.w = fmaxf(tb[px*257 + oc4*4+3] + b2[oc4*4+3], 0.f);
    *(float4*)&hpad[((size_t)b*NPP + pp)*256 + oc4*4] = v;   // raw (pre-BN2)
  }
}

// ---- BN2 stats over hpad NHWC interior (thread = channel, coalesced) ----
__global__ __launch_bounds__(256) void k_bnstats2(const float* __restrict__ hpad,
                                                  float* __restrict__ sum2){
  int c = threadIdx.x;
  int q0 = blockIdx.x*98;               // 256 blocks * 98 px = 25088
  float s1=0.f, s2=0.f;
  for(int qi=0; qi<98; qi++){
    int q = q0+qi; int b = q/NP2; int pix = q - b*NP2;
    int pp = (pix/112 + 1)*114 + (pix%112) + 1;
    float v = hpad[((size_t)b*NPP + pp)*256 + c];
    s1 += v; s2 += v*v;
  }
  atomicAdd(&sum2[c], s1); atomicAdd(&sum2[256+c], s2);
}

__global__ void k_fin2(const float* __restrict__ sum2, const float* __restrict__ g2,
                       const float* __restrict__ be2, float* __restrict__ stats2){
  int ch = threadIdx.x;                 // 256
  float n = 2.f*(float)NP2;
  float mean = sum2[ch]/n;
  float var  = sum2[256+ch]/n - mean*mean;
  float sc = g2[ch]/sqrtf(var + 1e-5f);
  stats2[ch]     = sc;
  stats2[256+ch] = be2[ch] - mean*sc;
}

// ---- in-place BN2 affine on hpad NHWC interior; zero border ----
__global__ void k_affine2(float* __restrict__ hpad, const float* __restrict__ stats2){
  int idx = blockIdx.x*256+threadIdx.x;    // 6653952
  int c = idx & 255; int pi = idx >> 8;
  int pp = pi % NPP;
  int row = pp/114, col = pp - row*114;
  bool in = (row>=1 && row<=112 && col>=1 && col<=112);
  hpad[idx] = in ? (stats2[c]*hpad[idx] + stats2[256+c]) : 0.f;
}

// ---- offset conv GEMM: M-tile 64, N=32(18), K=2304, k = n*256+c, coalesced f4 A ----
__global__ __launch_bounds__(256) void k_convoff(const float* __restrict__ hpad,
        const float* __restrict__ woff2, const float* __restrict__ boff, float* __restrict__ offb){
  __shared__ float Alds[32*65];         // [kk][p] stride 65
  __shared__ float Blds[1024];          // [kk][oc]
  const int tid = threadIdx.x;
  const int mbase = blockIdx.x*64;      // grid 392
  const int b = mbase/NP2; const int ijbase = mbase - b*NP2;
  const int oc = tid & 31; const int p0 = (tid>>5)*8;
  const float* hb = hpad + (size_t)b*NPP*256;
  float acc[8] = {};
  for(int kt=0; kt<72; kt++){
    int k0 = kt*32; int n = k0>>8; int c0 = k0&255;
    __syncthreads();
    ((float4*)Blds)[tid] = ((const float4*)(woff2 + (size_t)k0*32))[tid];
    #pragma unroll
    for(int it=0; it<2; it++){
      int id = it*256+tid;
      int p = id>>3, kq = id&7;          // 64 px x 8 c-quads
      int ij = ijbase+p; int i = ij/112, j = ij - i*112;
      int pp = (i + n/3)*114 + j + (n%3);
      float4 v = *(const float4*)(hb + (size_t)pp*256 + c0 + kq*4);   // 128B/8 lanes
      Alds[(kq*4+0)*65+p] = v.x;
      Alds[(kq*4+1)*65+p] = v.y;
      Alds[(kq*4+2)*65+p] = v.z;
      Alds[(kq*4+3)*65+p] = v.w;
    }
    __syncthreads();
    #pragma unroll
    for(int kk=0;kk<32;kk++){
      float bv = Blds[kk*32+oc];
      const float* ap = &Alds[kk*65+p0];
      #pragma unroll
      for(int i2=0;i2<8;i2++) acc[i2] = fmaf(ap[i2], bv, acc[i2]);
    }
  }
  if(oc<18){
    float bb = boff[oc];
    #pragma unroll
    for(int p=0;p<8;p++){
      int ij = ijbase+p0+p;
      offb[(size_t)(b*18+oc)*NP2 + ij] = acc[p]+bb;
    }
  }
}

// ---- deformable conv: MFMA bf16, M-tile 32, N=256, K=2304 (k = n*256+c) ----
__global__ __launch_bounds__(256) void k_deform(
    const float* __restrict__ hpad,                 // NHWC fp32, affine'd, zero border
    const float* __restrict__ offb,                 // NCHW fp32
    const unsigned short* __restrict__ w4f,         // frag-ready bf16 [72][256][32]
    float* __restrict__ out){
  __shared__ int   gidx[32][9][4];
  __shared__ float gwt [32][9][4];
  __shared__ unsigned short afrag[2][1024];
  const int tid = threadIdx.x;
  const int wave = tid>>6, lane = tid&63;
  const int pix0 = blockIdx.x*32;                   // grid 784
  const int b = pix0/NP2, ij0 = pix0 - b*NP2;

  for(int t=tid; t<288; t+=256){
    int p = t/9, n = t - 9*(t/9);
    int ij = ij0+p; int i = ij/112, j = ij - i*112;
    float ox = offb[(size_t)(b*18 + 2*n  )*NP2 + ij];
    float oy = offb[(size_t)(b*18 + 2*n+1)*NP2 + ij];
    float px = (float)(i + n/3) + ox;
    float py = (float)(j + n%3) + oy;
    float fpx = floorf(px), fpy = floorf(py);
    float qltxf = fminf(fmaxf(fpx,     0.f),113.f);
    float qltyf = fminf(fmaxf(fpy,     0.f),113.f);
    float qrbxf = fminf(fmaxf(fpx+1.f, 0.f),113.f);
    float qrbyf = fminf(fmaxf(fpy+1.f, 0.f),113.f);
    int qltx=(int)qltxf, qlty=(int)qltyf, qrbx=(int)qrbxf, qrby=(int)qrbyf;
    bool mx = (px<1.f)||(px>112.f);
    bool my = (py<1.f)||(py>112.f);
    float pxc = fminf(fmaxf(mx?fpx:px, 0.f),113.f);
    float pyc = fminf(fmaxf(my?fpy:py, 0.f),113.f);
    float glt = (1.f+(qltxf-pxc))*(1.f+(qltyf-pyc));
    float grb = (1.f-(qrbxf-pxc))*(1.f-(qrbyf-pyc));
    float glb = (1.f+(qltxf-pxc))*(1.f-(qrbyf-pyc));
    float grt = (1.f-(qrbxf-pxc))*(1.f+(qltyf-pyc));
    gidx[p][n][0]=qltx*114+qlty; gwt[p][n][0]=glt;
    gidx[p][n][1]=qrbx*114+qrby; gwt[p][n][1]=grb;
    gidx[p][n][2]=qltx*114+qrby; gwt[p][n][2]=glb;  // (lt_x, rb_y)
    gidx[p][n][3]=qrbx*114+qlty; gwt[p][n][3]=grt;  // (rb_x, lt_y)
  }

  const int px_g   = ((tid>>7)<<4) | ((tid>>1)&15);
  const int coff_g = (((tid>>5)&3)<<3) + ((tid&1)<<2);
  const float* hb = hpad + (size_t)b*NPP*256;

  f32x4 acc[2][4] = {};
  __syncthreads();

  auto GATHER = [&](int kt, int buf){
    int k0 = kt*32; int n = k0>>8; int cb = (k0&255) + coff_g;
    const int*   gi = gidx[px_g][n];
    const float* gw = gwt[px_g][n];
    f32x4 v = {0.f,0.f,0.f,0.f};
    #pragma unroll
    for(int cr=0;cr<4;cr++){
      const f32x4 s = *(const f32x4*)(hb + (size_t)gi[cr]*256 + cb);
      float w = gw[cr];
      v.x = fmaf(w, s.x, v.x); v.y = fmaf(w, s.y, v.y);
      v.z = fmaf(w, s.z, v.z); v.w = fmaf(w, s.w, v.w);
    }
    uint2 u;
    u.x = (unsigned)f2bu(v.x) | ((unsigned)f2bu(v.y)<<16);
    u.y = (unsigned)f2bu(v.z) | ((unsigned)f2bu(v.w)<<16);
    *(uint2*)&afrag[buf][tid*4] = u;
  };

  GATHER(0, 0);
  for(int kt=0; kt<72; kt++){
    __syncthreads();
    if(kt+1 < 72) GATHER(kt+1, (kt+1)&1);
    const unsigned short* ab = afrag[kt&1];
    short8 aF0 = *(const short8*)&ab[lane*8];
    short8 aF1 = *(const short8*)&ab[(64+lane)*8];
    const unsigned short* wb = w4f + (size_t)kt*8192 + ((lane>>4)<<3);
    #pragma unroll
    for(int nf=0; nf<4; nf++){
      int oc = wave*64 + nf*16 + (lane&15);
      short8 bF = *(const short8*)&wb[oc*32];
      acc[0][nf] = __builtin_amdgcn_mfma_f32_16x16x32_bf16(aF0, bF, acc[0][nf], 0,0,0);
      acc[1][nf] = __builtin_amdgcn_mfma_f32_16x16x32_bf16(aF1, bF, acc[1][nf], 0,0,0);
    }
  }
  int row0 = ((lane>>4)<<2);
  int col  = lane&15;
  #pragma unroll
  for(int mf=0; mf<2; mf++)
    #pragma unroll
    for(int nf=0; nf<4; nf++){
      int oc = wave*64 + nf*16 + col;
      size_t ob = (size_t)(b*256+oc)*NP2 + ij0 + mf*16 + row0;
      *(f32x4*)(out + ob) = acc[mf][nf];
    }
}

extern "C" void kernel_launch(void* const* d_in, const int* in_sizes, int n_in,
                              void* d_out, int out_size, void* d_ws, size_t ws_size,
                              hipStream_t stream){
  (void)in_sizes; (void)n_in;
  const float* x    = (const float*)d_in[0];
  const float* w1   = (const float*)d_in[1];
  const float* b1   = (const float*)d_in[2];
  const float* g1   = (const float*)d_in[3];
  const float* be1  = (const float*)d_in[4];
  const float* w2   = (const float*)d_in[5];
  const float* b2   = (const float*)d_in[6];
  const float* g2   = (const float*)d_in[7];
  const float* be2  = (const float*)d_in[8];
  const float* woff = (const float*)d_in[9];
  const float* boff = (const float*)d_in[10];
  const float* w4   = (const float*)d_in[11];
  float* out = (float*)d_out;
  float* ws = (float*)d_ws;

  if(ws_size < WS_NEED_BYTES){
    hipMemsetAsync(d_out, 0, (size_t)out_size*sizeof(float), stream);
    return;
  }

  float* sum1   = ws + S_SUM1;
  float* sum2   = ws + S_SUM2;
  float* stats1 = ws + S_STATS1;
  float* stats2 = ws + S_STATS2;
  float* w2T    = ws + S_W2T;
  float* woff2  = ws + S_WOFF2;
  unsigned short* w4f = (unsigned short*)(ws + S_W4F);
  float* offb   = ws + S_OFFB;
  float* ppad   = ws + S_PPAD;
  float* hpad   = ws + S_HPAD;

  hipMemsetAsync(sum1, 0, 640*sizeof(float), stream);   // sum1(128) + sum2(512)
  k_w2T      <<<576,   256, 0, stream>>>(w2, w2T);
  k_w4f      <<<2304,  256, 0, stream>>>(w4, w4f);
  k_woff2    <<<288,   256, 0, stream>>>(woff, woff2);
  k_conv1pool<<<6272,  256, 0, stream>>>(x, w1, b1, ppad, sum1);
  k_fin1     <<<1,     64,  0, stream>>>(sum1, g1, be1, stats1);
  k_affine1  <<<6498,  256, 0, stream>>>(ppad, stats1);
  k_conv2    <<<784,   256, 0, stream>>>(ppad, w2T, b2, hpad);
  k_bnstats2 <<<256,   256, 0, stream>>>(hpad, sum2);
  k_fin2     <<<1,     256, 0, stream>>>(sum2, g2, be2, stats2);
  k_affine2  <<<25992, 256, 0, stream>>>(hpad, stats2);
  k_convoff  <<<392,   256, 0, stream>>>(hpad, woff2, boff, offb);
  k_deform   <<<784,   256, 0, stream>>>(hpad, offb, w4f, out);
}

// Round 9
// 568.052 us; speedup vs baseline: 1.0839x; 1.0839x over previous
//
#include <hip/hip_runtime.h>
#include <hip/hip_bf16.h>

#define NP1 50176      // 224*224
#define NP2 12544      // 112*112
#define NPP 12996      // 114*114 zero-padded map

typedef __attribute__((ext_vector_type(8))) short short8;   // 8 bf16 = 4 VGPRs
typedef __attribute__((ext_vector_type(4))) float f32x4;

__device__ __forceinline__ unsigned short f2bu(float f){
  __hip_bfloat16 h = __float2bfloat16(f);
  return *reinterpret_cast<unsigned short*>(&h);
}

// ---- workspace layout (float slots) ----
#define S_SUM1   0          // 128
#define S_SUM2   128        // 512
#define S_STATS1 640        // 128
#define S_STATS2 768        // 512
#define S_W2T    1280       // 576*256 = 147456 fp32
#define S_WOFF2  148736     // 2304*32 = 73728 fp32 (k = n*256+c order)
#define S_W4F    222464     // 589824 bf16 -> 294912 slots (frag-ready [kt][oc][kk], k = n*256+c)
#define S_OFFB   517376     // 2*18*112*112 = 451584 fp32 (NCHW)
#define S_PPAD   968960     // 2*64*114*114 = 1663488 fp32 (NCHW padded)
#define S_HPAD   2632448    // 2*114*114*256 = 6653952 fp32 (NHWC padded)
#define S_PBUF   9286400    // 9*451584 = 4064256 fp32 (per-tap partials)
#define WS_NEED_FLOATS 13350656ull
#define WS_NEED_BYTES  (WS_NEED_FLOATS*4ull)   // 53.4 MB (ws is ~256MB per R7 fill evidence)

// ---------- weight prep ----------
__global__ void k_w2T(const float* __restrict__ w2, float* __restrict__ w2T){
  int idx = blockIdx.x*256+threadIdx.x;  int kk = idx>>8, oc = idx&255;   // k = c*9+n
  w2T[idx] = w2[oc*576 + kk];
}
// w4 frag-ready bf16: w4f[kt*8192 + oc*32 + kk] = w4[oc][c][n], k = kt*32+kk = n*256+c
__global__ void k_w4f(const float* __restrict__ w4, unsigned short* __restrict__ w4f){
  int idx = blockIdx.x*256+threadIdx.x;        // 589824
  int kt = idx/8192; int r = idx - kt*8192;
  int oc = r>>5, kk = r&31;
  int k = kt*32 + kk; int n = k>>8, c = k&255;
  w4f[idx] = f2bu(w4[oc*2304 + c*9 + n]);
}
// woff2[k][oc], k = n*256+c, oc padded to 32
__global__ void k_woff2(const float* __restrict__ woff, float* __restrict__ woff2){
  int idx = blockIdx.x*256+threadIdx.x;        // 73728
  int k = idx>>5, oc = idx&31;
  int n = k>>8, c = k&255;
  woff2[idx] = (oc<18) ? woff[oc*2304 + c*9 + n] : 0.f;
}

// ---- conv1+bias+ReLU + 2x2 avgpool, LDS x-tile; BN1 partial stats ----
__global__ __launch_bounds__(256) void k_conv1pool(
    const float* __restrict__ x, const float* __restrict__ w1, const float* __restrict__ b1,
    float* __restrict__ ppad, float* __restrict__ sum1){
  __shared__ float xs[3*34*34];         // 13872 B
  int bid = blockIdx.x;                 // 6272 = 2*64*49
  int tile = bid % 49; int oc = (bid/49) & 63; int b = bid/(49*64);
  int tu = tile/7, tv = tile - 7*(tile/7);
  int tid = threadIdx.x;
  int in0 = tu*32 - 1, jn0 = tv*32 - 1;
  for(int t=tid; t<3468; t+=256){
    int c = t/1156; int r2 = t - c*1156; int rr = r2/34; int cc = r2 - rr*34;
    int ii = in0+rr, jj = jn0+cc;
    xs[t] = (ii>=0 && ii<224 && jj>=0 && jj<224) ? x[(size_t)(b*3+c)*NP1 + ii*224+jj] : 0.f;
  }
  float w[27];
  #pragma unroll
  for(int t=0;t<27;t++) w[t] = w1[oc*27+t];
  float bia = b1[oc];
  __syncthreads();
  int u = tid>>4, v = tid&15;           // local pooled coords
  float s1=0.f, s2=0.f, pl=0.f;
  #pragma unroll
  for(int dy=0;dy<2;dy++){
    #pragma unroll
    for(int dx=0;dx<2;dx++){
      float acc = bia;
      #pragma unroll
      for(int c=0;c<3;c++)
        #pragma unroll
        for(int kh=0;kh<3;kh++)
          #pragma unroll
          for(int kw=0;kw<3;kw++)
            acc += xs[c*1156 + (2*u+dy+kh)*34 + (2*v+dx+kw)] * w[c*9+kh*3+kw];
      acc = fmaxf(acc, 0.f);            // relu BEFORE BN
      pl += acc; s1 += acc; s2 += acc*acc;
    }
  }
  int U = tu*16+u, V = tv*16+v;
  ppad[(size_t)(b*64+oc)*NPP + (U+1)*114 + (V+1)] = 0.25f*pl;
  __shared__ float r1[256], r2[256];
  r1[tid]=s1; r2[tid]=s2; __syncthreads();
  for(int o=128;o>0;o>>=1){
    if(tid<o){ r1[tid]+=r1[tid+o]; r2[tid]+=r2[tid+o]; }
    __syncthreads();
  }
  if(tid==0){ atomicAdd(&sum1[oc], r1[0]); atomicAdd(&sum1[64+oc], r2[0]); }
}

__global__ void k_fin1(const float* __restrict__ sum1, const float* __restrict__ g1,
                       const float* __restrict__ be1, float* __restrict__ stats1){
  int ch = threadIdx.x;                 // 64
  float n = 2.f*(float)NP1;
  float mean = sum1[ch]/n;
  float var  = sum1[64+ch]/n - mean*mean;
  float sc = g1[ch]/sqrtf(var + 1e-5f);
  stats1[ch]    = sc;
  stats1[64+ch] = be1[ch] - mean*sc;
}

// ---- in-place BN1 affine on ppad interior; zero border ----
__global__ void k_affine1(float* __restrict__ ppad, const float* __restrict__ stats1){
  int idx = blockIdx.x*256+threadIdx.x;    // 1663488
  int yp = idx % 114; int t = idx/114; int xp = t % 114; t /= 114;
  int c = t & 63;
  bool in = (xp>=1 && xp<=112 && yp>=1 && yp<=112);
  ppad[idx] = in ? (stats1[c]*ppad[idx] + stats1[64+c]) : 0.f;
}

// ---- conv2 GEMM: M=25088,N=256,K=576; bias+relu RAW -> hpad NHWC interior ----
__global__ __launch_bounds__(256) void k_conv2(const float* __restrict__ ppad,
        const float* __restrict__ w2T, const float* __restrict__ b2, float* __restrict__ hpad){
  __shared__ float smem[9216];          // Alds[0,1024) | Blds[1024,9216); tb reuses [0,8224)
  float* Alds = smem; float* Blds = smem+1024; float* tb = smem;
  const int tid = threadIdx.x;
  const int mbase = blockIdx.x*32;
  const int b = mbase/NP2; const int ijbase = mbase - b*NP2;
  const int oc0 = (tid & 31)*8;
  const int p0  = (tid >> 5)*4;
  const float* pb = ppad + (size_t)b*64*NPP;
  float acc[4][8] = {};
  for(int k0=0;k0<576;k0+=32){
    __syncthreads();
    { const float4* src = (const float4*)(w2T + k0*256);
      float4* dst = (float4*)Blds;
      #pragma unroll
      for(int r=0;r<8;r++) dst[r*256+tid] = src[r*256+tid]; }
    #pragma unroll
    for(int r=0;r<4;r++){
      int e = r*256+tid;
      int kk = e>>5, p = e&31;
      int k = k0+kk; int c = k/9; int n = k - 9*c;
      int ij = ijbase+p; int i = ij/112, j = ij - i*112;
      Alds[kk*32+p] = pb[(c*114 + i + n/3)*114 + j + (n%3)];
    }
    __syncthreads();
    #pragma unroll
    for(int kk=0;kk<32;kk++){
      float a0=Alds[kk*32+p0+0], a1=Alds[kk*32+p0+1], a2=Alds[kk*32+p0+2], a3=Alds[kk*32+p0+3];
      const float* bp = &Blds[kk*256+oc0];
      #pragma unroll
      for(int o=0;o<8;o++){
        float bv = bp[o];
        acc[0][o]=fmaf(a0,bv,acc[0][o]); acc[1][o]=fmaf(a1,bv,acc[1][o]);
        acc[2][o]=fmaf(a2,bv,acc[2][o]); acc[3][o]=fmaf(a3,bv,acc[3][o]);
      }
    }
  }
  __syncthreads();
  #pragma unroll
  for(int p=0;p<4;p++)
    #pragma unroll
    for(int o=0;o<8;o++) tb[(p0+p)*257 + oc0+o] = acc[p][o];
  __syncthreads();
  #pragma unroll
  for(int it=0; it<8; it++){
    int id = it*256 + tid;
    int px = id>>6, oc4 = id&63;
    int ij = ijbase+px; int i = ij/112, j = ij - i*112;
    int pp = (i+1)*114 + (j+1);
    float4 v;
    v.x = fmaxf(tb[px*257 + oc4*4+0] + b2[oc4*4+0], 0.f);
    v.y = fmaxf(tb[px*257 + oc4*4+1] + b2[oc4*4+1], 0.f);
    v.z = fmaxf(tb[px*257 + oc4*4+2] + b2[oc4*4+2], 0.f);
    v.w = fmaxf(tb[px*257 + oc4*4+3] + b2[oc4*4+3], 0.f);
    *(float4*)&hpad[((size_t)b*NPP + pp)*256 + oc4*4] = v;   // raw (pre-BN2)
  }
}

// ---- BN2 stats over hpad NHWC interior (thread = channel, coalesced) ----
__global__ __launch_bounds__(256) void k_bnstats2(const float* __restrict__ hpad,
                                                  float* __restrict__ sum2){
  int c = threadIdx.x;
  int q0 = blockIdx.x*98;               // 256 blocks * 98 px = 25088
  float s1=0.f, s2=0.f;
  for(int qi=0; qi<98; qi++){
    int q = q0+qi; int b = q/NP2; int pix = q - b*NP2;
    int pp = (pix/112 + 1)*114 + (pix%112) + 1;
    float v = hpad[((size_t)b*NPP + pp)*256 + c];
    s1 += v; s2 += v*v;
  }
  atomicAdd(&sum2[c], s1); atomicAdd(&sum2[256+c], s2);
}

__global__ void k_fin2(const float* __restrict__ sum2, const float* __restrict__ g2,
                       const float* __restrict__ be2, float* __restrict__ stats2){
  int ch = threadIdx.x;                 // 256
  float n = 2.f*(float)NP2;
  float mean = sum2[ch]/n;
  float var  = sum2[256+ch]/n - mean*mean;
  float sc = g2[ch]/sqrtf(var + 1e-5f);
  stats2[ch]     = sc;
  stats2[256+ch] = be2[ch] - mean*sc;
}

// ---- in-place BN2 affine on hpad NHWC interior; zero border ----
__global__ void k_affine2(float* __restrict__ hpad, const float* __restrict__ stats2){
  int idx = blockIdx.x*256+threadIdx.x;    // 6653952
  int c = idx & 255; int pi = idx >> 8;
  int pp = pi % NPP;
  int row = pp/114, col = pp - row*114;
  bool in = (row>=1 && row<=112 && col>=1 && col<=112);
  hpad[idx] = in ? (stats2[c]*hpad[idx] + stats2[256+c]) : 0.f;
}

// ---- offset conv, SPLIT-K over the 9 taps: grid 9*392, per-tap partials ----
__global__ __launch_bounds__(256) void k_convoff_split(const float* __restrict__ hpad,
        const float* __restrict__ woff2, float* __restrict__ pbuf){
  __shared__ float Alds[32*65];         // [kk][p] stride 65
  __shared__ float Blds[1024];          // [kk][oc]
  const int tid = threadIdx.x;
  const int bx = blockIdx.x;            // 3528 = 9*392
  const int n  = bx/392;                // tap
  const int mt = bx - n*392;
  const int mbase = mt*64;
  const int b = mbase/NP2; const int ijbase = mbase - b*NP2;
  const int oc = tid & 31; const int p0 = (tid>>5)*8;
  const float* hb = hpad + (size_t)b*NPP*256;
  float acc[8] = {};
  for(int kt=0; kt<8; kt++){            // K-chunk: c = kt*32 .. +31 within tap n
    int c0 = kt*32;
    __syncthreads();
    ((float4*)Blds)[tid] = ((const float4*)(woff2 + ((size_t)n*256 + c0)*32))[tid];
    #pragma unroll
    for(int it=0; it<2; it++){
      int id = it*256+tid;
      int p = id>>3, kq = id&7;          // 64 px x 8 c-quads
      int ij = ijbase+p; int i = ij/112, j = ij - i*112;
      int pp = (i + n/3)*114 + j + (n%3);
      float4 v = *(const float4*)(hb + (size_t)pp*256 + c0 + kq*4);
      Alds[(kq*4+0)*65+p] = v.x;
      Alds[(kq*4+1)*65+p] = v.y;
      Alds[(kq*4+2)*65+p] = v.z;
      Alds[(kq*4+3)*65+p] = v.w;
    }
    __syncthreads();
    #pragma unroll
    for(int kk=0;kk<32;kk++){
      float bv = Blds[kk*32+oc];
      const float* ap = &Alds[kk*65+p0];
      #pragma unroll
      for(int i2=0;i2<8;i2++) acc[i2] = fmaf(ap[i2], bv, acc[i2]);
    }
  }
  if(oc<18){
    #pragma unroll
    for(int p=0;p<8;p++){
      int ij = ijbase+p0+p;
      pbuf[(size_t)n*451584 + ((size_t)(b*18+oc))*NP2 + ij] = acc[p];
    }
  }
}

// ---- reduce the 9 per-tap partials (deterministic order) + bias ----
__global__ void k_offred(const float* __restrict__ pbuf, const float* __restrict__ boff,
                         float* __restrict__ offb){
  int idx = blockIdx.x*256+threadIdx.x;    // 451584
  int oc = (idx/NP2) % 18;
  float s = boff[oc];
  #pragma unroll
  for(int n=0;n<9;n++) s += pbuf[(size_t)n*451584 + idx];
  offb[idx] = s;
}

// ---- deformable conv: MFMA bf16, M-tile 32, N=256, K=2304 (k = n*256+c) ----
__global__ __launch_bounds__(256) void k_deform(
    const float* __restrict__ hpad,                 // NHWC fp32, affine'd, zero border
    const float* __restrict__ offb,                 // NCHW fp32
    const unsigned short* __restrict__ w4f,         // frag-ready bf16 [72][256][32]
    float* __restrict__ out){
  __shared__ int   gidx[32][9][4];
  __shared__ float gwt [32][9][4];
  __shared__ unsigned short afrag[2][1024];
  const int tid = threadIdx.x;
  const int wave = tid>>6, lane = tid&63;
  const int pix0 = blockIdx.x*32;                   // grid 784
  const int b = pix0/NP2, ij0 = pix0 - b*NP2;

  for(int t=tid; t<288; t+=256){
    int p = t/9, n = t - 9*(t/9);
    int ij = ij0+p; int i = ij/112, j = ij - i*112;
    float ox = offb[(size_t)(b*18 + 2*n  )*NP2 + ij];
    float oy = offb[(size_t)(b*18 + 2*n+1)*NP2 + ij];
    float px = (float)(i + n/3) + ox;
    float py = (float)(j + n%3) + oy;
    float fpx = floorf(px), fpy = floorf(py);
    float qltxf = fminf(fmaxf(fpx,     0.f),113.f);
    float qltyf = fminf(fmaxf(fpy,     0.f),113.f);
    float qrbxf = fminf(fmaxf(fpx+1.f, 0.f),113.f);
    float qrbyf = fminf(fmaxf(fpy+1.f, 0.f),113.f);
    int qltx=(int)qltxf, qlty=(int)qltyf, qrbx=(int)qrbxf, qrby=(int)qrbyf;
    bool mx = (px<1.f)||(px>112.f);
    bool my = (py<1.f)||(py>112.f);
    float pxc = fminf(fmaxf(mx?fpx:px, 0.f),113.f);
    float pyc = fminf(fmaxf(my?fpy:py, 0.f),113.f);
    float glt = (1.f+(qltxf-pxc))*(1.f+(qltyf-pyc));
    float grb = (1.f-(qrbxf-pxc))*(1.f-(qrbyf-pyc));
    float glb = (1.f+(qltxf-pxc))*(1.f-(qrbyf-pyc));
    float grt = (1.f-(qrbxf-pxc))*(1.f+(qltyf-pyc));
    gidx[p][n][0]=qltx*114+qlty; gwt[p][n][0]=glt;
    gidx[p][n][1]=qrbx*114+qrby; gwt[p][n][1]=grb;
    gidx[p][n][2]=qltx*114+qrby; gwt[p][n][2]=glb;  // (lt_x, rb_y)
    gidx[p][n][3]=qrbx*114+qlty; gwt[p][n][3]=grt;  // (rb_x, lt_y)
  }

  const int px_g   = ((tid>>7)<<4) | ((tid>>1)&15);
  const int coff_g = (((tid>>5)&3)<<3) + ((tid&1)<<2);
  const float* hb = hpad + (size_t)b*NPP*256;

  f32x4 acc[2][4] = {};
  __syncthreads();

  auto GATHER = [&](int kt, int buf){
    int k0 = kt*32; int n = k0>>8; int cb = (k0&255) + coff_g;
    const int*   gi = gidx[px_g][n];
    const float* gw = gwt[px_g][n];
    f32x4 v = {0.f,0.f,0.f,0.f};
    #pragma unroll
    for(int cr=0;cr<4;cr++){
      const f32x4 s = *(const f32x4*)(hb + (size_t)gi[cr]*256 + cb);
      float w = gw[cr];
      v.x = fmaf(w, s.x, v.x); v.y = fmaf(w, s.y, v.y);
      v.z = fmaf(w, s.z, v.z); v.w = fmaf(w, s.w, v.w);
    }
    uint2 u;
    u.x = (unsigned)f2bu(v.x) | ((unsigned)f2bu(v.y)<<16);
    u.y = (unsigned)f2bu(v.z) | ((unsigned)f2bu(v.w)<<16);
    *(uint2*)&afrag[buf][tid*4] = u;
  };

  GATHER(0, 0);
  for(int kt=0; kt<72; kt++){
    __syncthreads();
    if(kt+1 < 72) GATHER(kt+1, (kt+1)&1);
    const unsigned short* ab = afrag[kt&1];
    short8 aF0 = *(const short8*)&ab[lane*8];
    short8 aF1 = *(const short8*)&ab[(64+lane)*8];
    const unsigned short* wb = w4f + (size_t)kt*8192 + ((lane>>4)<<3);
    #pragma unroll
    for(int nf=0; nf<4; nf++){
      int oc = wave*64 + nf*16 + (lane&15);
      short8 bF = *(const short8*)&wb[oc*32];
      acc[0][nf] = __builtin_amdgcn_mfma_f32_16x16x32_bf16(aF0, bF, acc[0][nf], 0,0,0);
      acc[1][nf] = __builtin_amdgcn_mfma_f32_16x16x32_bf16(aF1, bF, acc[1][nf], 0,0,0);
    }
  }
  int row0 = ((lane>>4)<<2);
  int col  = lane&15;
  #pragma unroll
  for(int mf=0; mf<2; mf++)
    #pragma unroll
    for(int nf=0; nf<4; nf++){
      int oc = wave*64 + nf*16 + col;
      size_t ob = (size_t)(b*256+oc)*NP2 + ij0 + mf*16 + row0;
      *(f32x4*)(out + ob) = acc[mf][nf];
    }
}

extern "C" void kernel_launch(void* const* d_in, const int* in_sizes, int n_in,
                              void* d_out, int out_size, void* d_ws, size_t ws_size,
                              hipStream_t stream){
  (void)in_sizes; (void)n_in;
  const float* x    = (const float*)d_in[0];
  const float* w1   = (const float*)d_in[1];
  const float* b1   = (const float*)d_in[2];
  const float* g1   = (const float*)d_in[3];
  const float* be1  = (const float*)d_in[4];
  const float* w2   = (const float*)d_in[5];
  const float* b2   = (const float*)d_in[6];
  const float* g2   = (const float*)d_in[7];
  const float* be2  = (const float*)d_in[8];
  const float* woff = (const float*)d_in[9];
  const float* boff = (const float*)d_in[10];
  const float* w4   = (const float*)d_in[11];
  float* out = (float*)d_out;
  float* ws = (float*)d_ws;

  if(ws_size < WS_NEED_BYTES){
    hipMemsetAsync(d_out, 0, (size_t)out_size*sizeof(float), stream);
    return;
  }

  float* sum1   = ws + S_SUM1;
  float* sum2   = ws + S_SUM2;
  float* stats1 = ws + S_STATS1;
  float* stats2 = ws + S_STATS2;
  float* w2T    = ws + S_W2T;
  float* woff2  = ws + S_WOFF2;
  unsigned short* w4f = (unsigned short*)(ws + S_W4F);
  float* offb   = ws + S_OFFB;
  float* ppad   = ws + S_PPAD;
  float* hpad   = ws + S_HPAD;
  float* pbuf   = ws + S_PBUF;

  hipMemsetAsync(sum1, 0, 640*sizeof(float), stream);   // sum1(128) + sum2(512)
  k_w2T          <<<576,   256, 0, stream>>>(w2, w2T);
  k_w4f          <<<2304,  256, 0, stream>>>(w4, w4f);
  k_woff2        <<<288,   256, 0, stream>>>(woff, woff2);
  k_conv1pool    <<<6272,  256, 0, stream>>>(x, w1, b1, ppad, sum1);
  k_fin1         <<<1,     64,  0, stream>>>(sum1, g1, be1, stats1);
  k_affine1      <<<6498,  256, 0, stream>>>(ppad, stats1);
  k_conv2        <<<784,   256, 0, stream>>>(ppad, w2T, b2, hpad);
  k_bnstats2     <<<256,   256, 0, stream>>>(hpad, sum2);
  k_fin2         <<<1,     256, 0, stream>>>(sum2, g2, be2, stats2);
  k_affine2      <<<25992, 256, 0, stream>>>(hpad, stats2);
  k_convoff_split<<<3528,  256, 0, stream>>>(hpad, woff2, pbuf);
  k_offred       <<<1764,  256, 0, stream>>>(pbuf, boff, offb);
  k_deform       <<<784,   256, 0, stream>>>(hpad, offb, w4f, out);
}

// Round 10
// 568.029 us; speedup vs baseline: 1.0840x; 1.0000x over previous
//
#include <hip/hip_runtime.h>
#include <hip/hip_bf16.h>

#define NP1 50176      // 224*224
#define NP2 12544      // 112*112
#define NPP 12996      // 114*114 zero-padded map

typedef __attribute__((ext_vector_type(8))) short short8;   // 8 bf16 = 4 VGPRs
typedef __attribute__((ext_vector_type(4))) float f32x4;

__device__ __forceinline__ unsigned short f2bu(float f){
  __hip_bfloat16 h = __float2bfloat16(f);
  return *reinterpret_cast<unsigned short*>(&h);
}

// ---- workspace layout (float slots) ----
#define S_SUM1   0          // 128
#define S_SUM2   128        // 512
#define S_STATS1 640        // 128
#define S_STATS2 768        // 512
#define S_W2T    1280       // 576*256 = 147456 fp32
#define S_WOFF2  148736     // 2304*32 = 73728 fp32 (k = n*256+c order)
#define S_W4F    222464     // 589824 bf16 -> 294912 slots (frag-ready [kt][oc][kk], k = n*256+c)
#define S_OFFB   517376     // 2*18*112*112 = 451584 fp32 (NCHW)
#define S_PPAD   968960     // 2*64*114*114 = 1663488 fp32 (NCHW padded)
#define S_HPAD   2632448    // 2*114*114*256 = 6653952 fp32 (NHWC padded)
#define S_PBUF   9286400    // 9*451584 = 4064256 fp32 (per-tap partials)
#define WS_NEED_FLOATS 13350656ull
#define WS_NEED_BYTES  (WS_NEED_FLOATS*4ull)   // 53.4 MB

// ---------- weight prep ----------
__global__ void k_w2T(const float* __restrict__ w2, float* __restrict__ w2T){
  int idx = blockIdx.x*256+threadIdx.x;  int kk = idx>>8, oc = idx&255;   // k = c*9+n
  w2T[idx] = w2[oc*576 + kk];
}
// w4 frag-ready bf16: w4f[kt*8192 + oc*32 + kk] = w4[oc][c][n], k = kt*32+kk = n*256+c
__global__ void k_w4f(const float* __restrict__ w4, unsigned short* __restrict__ w4f){
  int idx = blockIdx.x*256+threadIdx.x;        // 589824
  int kt = idx/8192; int r = idx - kt*8192;
  int oc = r>>5, kk = r&31;
  int k = kt*32 + kk; int n = k>>8, c = k&255;
  w4f[idx] = f2bu(w4[oc*2304 + c*9 + n]);
}
// woff2[k][oc], k = n*256+c, oc padded to 32
__global__ void k_woff2(const float* __restrict__ woff, float* __restrict__ woff2){
  int idx = blockIdx.x*256+threadIdx.x;        // 73728
  int k = idx>>5, oc = idx&31;
  int n = k>>8, c = k&255;
  woff2[idx] = (oc<18) ? woff[oc*2304 + c*9 + n] : 0.f;
}

// ---- conv1+bias+ReLU + 2x2 avgpool, LDS x-tile; BN1 partial stats ----
__global__ __launch_bounds__(256) void k_conv1pool(
    const float* __restrict__ x, const float* __restrict__ w1, const float* __restrict__ b1,
    float* __restrict__ ppad, float* __restrict__ sum1){
  __shared__ float xs[3*34*34];         // 13872 B
  int bid = blockIdx.x;                 // 6272 = 2*64*49
  int tile = bid % 49; int oc = (bid/49) & 63; int b = bid/(49*64);
  int tu = tile/7, tv = tile - 7*(tile/7);
  int tid = threadIdx.x;
  int in0 = tu*32 - 1, jn0 = tv*32 - 1;
  for(int t=tid; t<3468; t+=256){
    int c = t/1156; int r2 = t - c*1156; int rr = r2/34; int cc = r2 - rr*34;
    int ii = in0+rr, jj = jn0+cc;
    xs[t] = (ii>=0 && ii<224 && jj>=0 && jj<224) ? x[(size_t)(b*3+c)*NP1 + ii*224+jj] : 0.f;
  }
  float w[27];
  #pragma unroll
  for(int t=0;t<27;t++) w[t] = w1[oc*27+t];
  float bia = b1[oc];
  __syncthreads();
  int u = tid>>4, v = tid&15;           // local pooled coords
  float s1=0.f, s2=0.f, pl=0.f;
  #pragma unroll
  for(int dy=0;dy<2;dy++){
    #pragma unroll
    for(int dx=0;dx<2;dx++){
      float acc = bia;
      #pragma unroll
      for(int c=0;c<3;c++)
        #pragma unroll
        for(int kh=0;kh<3;kh++)
          #pragma unroll
          for(int kw=0;kw<3;kw++)
            acc += xs[c*1156 + (2*u+dy+kh)*34 + (2*v+dx+kw)] * w[c*9+kh*3+kw];
      acc = fmaxf(acc, 0.f);            // relu BEFORE BN
      pl += acc; s1 += acc; s2 += acc*acc;
    }
  }
  int U = tu*16+u, V = tv*16+v;
  ppad[(size_t)(b*64+oc)*NPP + (U+1)*114 + (V+1)] = 0.25f*pl;
  __shared__ float r1[256], r2[256];
  r1[tid]=s1; r2[tid]=s2; __syncthreads();
  for(int o=128;o>0;o>>=1){
    if(tid<o){ r1[tid]+=r1[tid+o]; r2[tid]+=r2[tid+o]; }
    __syncthreads();
  }
  if(tid==0){ atomicAdd(&sum1[oc], r1[0]); atomicAdd(&sum1[64+oc], r2[0]); }
}

__global__ void k_fin1(const float* __restrict__ sum1, const float* __restrict__ g1,
                       const float* __restrict__ be1, float* __restrict__ stats1){
  int ch = threadIdx.x;                 // 64
  float n = 2.f*(float)NP1;
  float mean = sum1[ch]/n;
  float var  = sum1[64+ch]/n - mean*mean;
  float sc = g1[ch]/sqrtf(var + 1e-5f);
  stats1[ch]    = sc;
  stats1[64+ch] = be1[ch] - mean*sc;
}

// ---- in-place BN1 affine on ppad interior; zero border ----
__global__ void k_affine1(float* __restrict__ ppad, const float* __restrict__ stats1){
  int idx = blockIdx.x*256+threadIdx.x;    // 1663488
  int yp = idx % 114; int t = idx/114; int xp = t % 114; t /= 114;
  int c = t & 63;
  bool in = (xp>=1 && xp<=112 && yp>=1 && yp<=112);
  ppad[idx] = in ? (stats1[c]*ppad[idx] + stats1[64+c]) : 0.f;
}

// ---- conv2 GEMM: M=25088,N=256,K=576; bias+relu RAW -> hpad NHWC interior ----
__global__ __launch_bounds__(256) void k_conv2(const float* __restrict__ ppad,
        const float* __restrict__ w2T, const float* __restrict__ b2, float* __restrict__ hpad){
  __shared__ float smem[9216];          // Alds[0,1024) | Blds[1024,9216); tb reuses [0,8224)
  float* Alds = smem; float* Blds = smem+1024; float* tb = smem;
  const int tid = threadIdx.x;
  const int mbase = blockIdx.x*32;
  const int b = mbase/NP2; const int ijbase = mbase - b*NP2;
  const int oc0 = (tid & 31)*8;
  const int p0  = (tid >> 5)*4;
  const float* pb = ppad + (size_t)b*64*NPP;
  float acc[4][8] = {};
  for(int k0=0;k0<576;k0+=32){
    __syncthreads();
    { const float4* src = (const float4*)(w2T + k0*256);
      float4* dst = (float4*)Blds;
      #pragma unroll
      for(int r=0;r<8;r++) dst[r*256+tid] = src[r*256+tid]; }
    #pragma unroll
    for(int r=0;r<4;r++){
      int e = r*256+tid;
      int kk = e>>5, p = e&31;
      int k = k0+kk; int c = k/9; int n = k - 9*c;
      int ij = ijbase+p; int i = ij/112, j = ij - i*112;
      Alds[kk*32+p] = pb[(c*114 + i + n/3)*114 + j + (n%3)];
    }
    __syncthreads();
    #pragma unroll
    for(int kk=0;kk<32;kk++){
      float a0=Alds[kk*32+p0+0], a1=Alds[kk*32+p0+1], a2=Alds[kk*32+p0+2], a3=Alds[kk*32+p0+3];
      const float* bp = &Blds[kk*256+oc0];
      #pragma unroll
      for(int o=0;o<8;o++){
        float bv = bp[o];
        acc[0][o]=fmaf(a0,bv,acc[0][o]); acc[1][o]=fmaf(a1,bv,acc[1][o]);
        acc[2][o]=fmaf(a2,bv,acc[2][o]); acc[3][o]=fmaf(a3,bv,acc[3][o]);
      }
    }
  }
  __syncthreads();
  #pragma unroll
  for(int p=0;p<4;p++)
    #pragma unroll
    for(int o=0;o<8;o++) tb[(p0+p)*257 + oc0+o] = acc[p][o];
  __syncthreads();
  #pragma unroll
  for(int it=0; it<8; it++){
    int id = it*256 + tid;
    int px = id>>6, oc4 = id&63;
    int ij = ijbase+px; int i = ij/112, j = ij - i*112;
    int pp = (i+1)*114 + (j+1);
    float4 v;
    v.x = fmaxf(tb[px*257 + oc4*4+0] + b2[oc4*4+0], 0.f);
    v.y = fmaxf(tb[px*257 + oc4*4+1] + b2[oc4*4+1], 0.f);
    v.z = fmaxf(tb[px*257 + oc4*4+2] + b2[oc4*4+2], 0.f);
    v.w = fmaxf(tb[px*257 + oc4*4+3] + b2[oc4*4+3], 0.f);
    *(float4*)&hpad[((size_t)b*NPP + pp)*256 + oc4*4] = v;   // raw (pre-BN2)
  }
}

// ---- BN2 stats over hpad NHWC interior (thread = channel, coalesced) ----
__global__ __launch_bounds__(256) void k_bnstats2(const float* __restrict__ hpad,
                                                  float* __restrict__ sum2){
  int c = threadIdx.x;
  int q0 = blockIdx.x*98;               // 256 blocks * 98 px = 25088
  float s1=0.f, s2=0.f;
  for(int qi=0; qi<98; qi++){
    int q = q0+qi; int b = q/NP2; int pix = q - b*NP2;
    int pp = (pix/112 + 1)*114 + (pix%112) + 1;
    float v = hpad[((size_t)b*NPP + pp)*256 + c];
    s1 += v; s2 += v*v;
  }
  atomicAdd(&sum2[c], s1); atomicAdd(&sum2[256+c], s2);
}

__global__ void k_fin2(const float* __restrict__ sum2, const float* __restrict__ g2,
                       const float* __restrict__ be2, float* __restrict__ stats2){
  int ch = threadIdx.x;                 // 256
  float n = 2.f*(float)NP2;
  float mean = sum2[ch]/n;
  float var  = sum2[256+ch]/n - mean*mean;
  float sc = g2[ch]/sqrtf(var + 1e-5f);
  stats2[ch]     = sc;
  stats2[256+ch] = be2[ch] - mean*sc;
}

// ---- in-place BN2 affine on hpad NHWC interior; zero border ----
__global__ void k_affine2(float* __restrict__ hpad, const float* __restrict__ stats2){
  int idx = blockIdx.x*256+threadIdx.x;    // 6653952
  int c = idx & 255; int pi = idx >> 8;
  int pp = pi % NPP;
  int row = pp/114, col = pp - row*114;
  bool in = (row>=1 && row<=112 && col>=1 && col<=112);
  hpad[idx] = in ? (stats2[c]*hpad[idx] + stats2[256+c]) : 0.f;
}

// ---- offset conv, SPLIT-K over 9 taps, XCD-swizzled: grid 3528 = 8 xcd * 441 ----
__global__ __launch_bounds__(256) void k_convoff_split(const float* __restrict__ hpad,
        const float* __restrict__ woff2, float* __restrict__ pbuf){
  __shared__ float Alds[32*65];         // [kk][p] stride 65
  __shared__ float Blds[1024];          // [kk][oc]
  const int tid = threadIdx.x;
  // XCD swizzle: same-XCD blocks (bid&7) cover a contiguous 49-strip region, all taps
  const int xcd = blockIdx.x & 7;
  const int r   = blockIdx.x >> 3;      // 0..440 = 9 taps * 49 strips
  const int n   = r/49;                 // tap
  const int mt  = xcd*49 + (r - n*49);  // strip 0..391
  const int mbase = mt*64;
  const int b = mbase/NP2; const int ijbase = mbase - b*NP2;
  const int oc = tid & 31; const int p0 = (tid>>5)*8;
  const float* hb = hpad + (size_t)b*NPP*256;
  float acc[8] = {};
  for(int kt=0; kt<8; kt++){            // K-chunk: c = kt*32 .. +31 within tap n
    int c0 = kt*32;
    __syncthreads();
    ((float4*)Blds)[tid] = ((const float4*)(woff2 + ((size_t)n*256 + c0)*32))[tid];
    #pragma unroll
    for(int it=0; it<2; it++){
      int id = it*256+tid;
      int p = id>>3, kq = id&7;          // 64 px x 8 c-quads
      int ij = ijbase+p; int i = ij/112, j = ij - i*112;
      int pp = (i + n/3)*114 + j + (n%3);
      float4 v = *(const float4*)(hb + (size_t)pp*256 + c0 + kq*4);
      Alds[(kq*4+0)*65+p] = v.x;
      Alds[(kq*4+1)*65+p] = v.y;
      Alds[(kq*4+2)*65+p] = v.z;
      Alds[(kq*4+3)*65+p] = v.w;
    }
    __syncthreads();
    #pragma unroll
    for(int kk=0;kk<32;kk++){
      float bv = Blds[kk*32+oc];
      const float* ap = &Alds[kk*65+p0];
      #pragma unroll
      for(int i2=0;i2<8;i2++) acc[i2] = fmaf(ap[i2], bv, acc[i2]);
    }
  }
  if(oc<18){
    #pragma unroll
    for(int p=0;p<8;p++){
      int ij = ijbase+p0+p;
      pbuf[(size_t)n*451584 + ((size_t)(b*18+oc))*NP2 + ij] = acc[p];
    }
  }
}

// ---- reduce the 9 per-tap partials (deterministic order) + bias ----
__global__ void k_offred(const float* __restrict__ pbuf, const float* __restrict__ boff,
                         float* __restrict__ offb){
  int idx = blockIdx.x*256+threadIdx.x;    // 451584
  int oc = (idx/NP2) % 18;
  float s = boff[oc];
  #pragma unroll
  for(int n=0;n<9;n++) s += pbuf[(size_t)n*451584 + idx];
  offb[idx] = s;
}

// ---- deformable conv: MFMA bf16, M-tile 32, XCD-swizzled grid 784 = 8*98 ----
__global__ __launch_bounds__(256) void k_deform(
    const float* __restrict__ hpad,                 // NHWC fp32, affine'd, zero border
    const float* __restrict__ offb,                 // NCHW fp32
    const unsigned short* __restrict__ w4f,         // frag-ready bf16 [72][256][32]
    float* __restrict__ out){
  __shared__ int   gidx[32][9][4];
  __shared__ float gwt [32][9][4];
  __shared__ unsigned short afrag[2][1024];
  const int tid = threadIdx.x;
  const int wave = tid>>6, lane = tid&63;
  // XCD swizzle: blocks on one XCD (bid&7) form a contiguous 98-strip (28-row) region
  // whose hpad footprint (~3.5MB + halo) fits the 4MB per-XCD L2.
  const int sidx = (blockIdx.x & 7)*98 + (blockIdx.x >> 3);
  const int pix0 = sidx*32;
  const int b = pix0/NP2, ij0 = pix0 - b*NP2;

  for(int t=tid; t<288; t+=256){
    int p = t/9, n = t - 9*(t/9);
    int ij = ij0+p; int i = ij/112, j = ij - i*112;
    float ox = offb[(size_t)(b*18 + 2*n  )*NP2 + ij];
    float oy = offb[(size_t)(b*18 + 2*n+1)*NP2 + ij];
    float px = (float)(i + n/3) + ox;
    float py = (float)(j + n%3) + oy;
    float fpx = floorf(px), fpy = floorf(py);
    float qltxf = fminf(fmaxf(fpx,     0.f),113.f);
    float qltyf = fminf(fmaxf(fpy,     0.f),113.f);
    float qrbxf = fminf(fmaxf(fpx+1.f, 0.f),113.f);
    float qrbyf = fminf(fmaxf(fpy+1.f, 0.f),113.f);
    int qltx=(int)qltxf, qlty=(int)qltyf, qrbx=(int)qrbxf, qrby=(int)qrbyf;
    bool mx = (px<1.f)||(px>112.f);
    bool my = (py<1.f)||(py>112.f);
    float pxc = fminf(fmaxf(mx?fpx:px, 0.f),113.f);
    float pyc = fminf(fmaxf(my?fpy:py, 0.f),113.f);
    float glt = (1.f+(qltxf-pxc))*(1.f+(qltyf-pyc));
    float grb = (1.f-(qrbxf-pxc))*(1.f-(qrbyf-pyc));
    float glb = (1.f+(qltxf-pxc))*(1.f-(qrbyf-pyc));
    float grt = (1.f-(qrbxf-pxc))*(1.f+(qltyf-pyc));
    gidx[p][n][0]=qltx*114+qlty; gwt[p][n][0]=glt;
    gidx[p][n][1]=qrbx*114+qrby; gwt[p][n][1]=grb;
    gidx[p][n][2]=qltx*114+qrby; gwt[p][n][2]=glb;  // (lt_x, rb_y)
    gidx[p][n][3]=qrbx*114+qlty; gwt[p][n][3]=grt;  // (rb_x, lt_y)
  }

  const int px_g   = ((tid>>7)<<4) | ((tid>>1)&15);
  const int coff_g = (((tid>>5)&3)<<3) + ((tid&1)<<2);
  const float* hb = hpad + (size_t)b*NPP*256;

  f32x4 acc[2][4] = {};
  __syncthreads();

  auto GATHER = [&](int kt, int buf){
    int k0 = kt*32; int n = k0>>8; int cb = (k0&255) + coff_g;
    const int*   gi = gidx[px_g][n];
    const float* gw = gwt[px_g][n];
    f32x4 v = {0.f,0.f,0.f,0.f};
    #pragma unroll
    for(int cr=0;cr<4;cr++){
      const f32x4 s = *(const f32x4*)(hb + (size_t)gi[cr]*256 + cb);
      float w = gw[cr];
      v.x = fmaf(w, s.x, v.x); v.y = fmaf(w, s.y, v.y);
      v.z = fmaf(w, s.z, v.z); v.w = fmaf(w, s.w, v.w);
    }
    uint2 u;
    u.x = (unsigned)f2bu(v.x) | ((unsigned)f2bu(v.y)<<16);
    u.y = (unsigned)f2bu(v.z) | ((unsigned)f2bu(v.w)<<16);
    *(uint2*)&afrag[buf][tid*4] = u;
  };

  GATHER(0, 0);
  for(int kt=0; kt<72; kt++){
    __syncthreads();
    if(kt+1 < 72) GATHER(kt+1, (kt+1)&1);
    const unsigned short* ab = afrag[kt&1];
    short8 aF0 = *(const short8*)&ab[lane*8];
    short8 aF1 = *(const short8*)&ab[(64+lane)*8];
    const unsigned short* wb = w4f + (size_t)kt*8192 + ((lane>>4)<<3);
    #pragma unroll
    for(int nf=0; nf<4; nf++){
      int oc = wave*64 + nf*16 + (lane&15);
      short8 bF = *(const short8*)&wb[oc*32];
      acc[0][nf] = __builtin_amdgcn_mfma_f32_16x16x32_bf16(aF0, bF, acc[0][nf], 0,0,0);
      acc[1][nf] = __builtin_amdgcn_mfma_f32_16x16x32_bf16(aF1, bF, acc[1][nf], 0,0,0);
    }
  }
  int row0 = ((lane>>4)<<2);
  int col  = lane&15;
  #pragma unroll
  for(int mf=0; mf<2; mf++)
    #pragma unroll
    for(int nf=0; nf<4; nf++){
      int oc = wave*64 + nf*16 + col;
      size_t ob = (size_t)(b*256+oc)*NP2 + ij0 + mf*16 + row0;
      *(f32x4*)(out + ob) = acc[mf][nf];
    }
}

extern "C" void kernel_launch(void* const* d_in, const int* in_sizes, int n_in,
                              void* d_out, int out_size, void* d_ws, size_t ws_size,
                              hipStream_t stream){
  (void)in_sizes; (void)n_in;
  const float* x    = (const float*)d_in[0];
  const float* w1   = (const float*)d_in[1];
  const float* b1   = (const float*)d_in[2];
  const float* g1   = (const float*)d_in[3];
  const float* be1  = (const float*)d_in[4];
  const float* w2   = (const float*)d_in[5];
  const float* b2   = (const float*)d_in[6];
  const float* g2   = (const float*)d_in[7];
  const float* be2  = (const float*)d_in[8];
  const float* woff = (const float*)d_in[9];
  const float* boff = (const float*)d_in[10];
  const float* w4   = (const float*)d_in[11];
  float* out = (float*)d_out;
  float* ws = (float*)d_ws;

  if(ws_size < WS_NEED_BYTES){
    hipMemsetAsync(d_out, 0, (size_t)out_size*sizeof(float), stream);
    return;
  }

  float* sum1   = ws + S_SUM1;
  float* sum2   = ws + S_SUM2;
  float* stats1 = ws + S_STATS1;
  float* stats2 = ws + S_STATS2;
  float* w2T    = ws + S_W2T;
  float* woff2  = ws + S_WOFF2;
  unsigned short* w4f = (unsigned short*)(ws + S_W4F);
  float* offb   = ws + S_OFFB;
  float* ppad   = ws + S_PPAD;
  float* hpad   = ws + S_HPAD;
  float* pbuf   = ws + S_PBUF;

  hipMemsetAsync(sum1, 0, 640*sizeof(float), stream);   // sum1(128) + sum2(512)
  k_w2T          <<<576,   256, 0, stream>>>(w2, w2T);
  k_w4f          <<<2304,  256, 0, stream>>>(w4, w4f);
  k_woff2        <<<288,   256, 0, stream>>>(woff, woff2);
  k_conv1pool    <<<6272,  256, 0, stream>>>(x, w1, b1, ppad, sum1);
  k_fin1         <<<1,     64,  0, stream>>>(sum1, g1, be1, stats1);
  k_affine1      <<<6498,  256, 0, stream>>>(ppad, stats1);
  k_conv2        <<<784,   256, 0, stream>>>(ppad, w2T, b2, hpad);
  k_bnstats2     <<<256,   256, 0, stream>>>(hpad, sum2);
  k_fin2         <<<1,     256, 0, stream>>>(sum2, g2, be2, stats2);
  k_affine2      <<<25992, 256, 0, stream>>>(hpad, stats2);
  k_convoff_split<<<3528,  256, 0, stream>>>(hpad, woff2, pbuf);
  k_offred       <<<1764,  256, 0, stream>>>(pbuf, boff, offb);
  k_deform       <<<784,   256, 0, stream>>>(hpad, offb, w4f, out);
}

// Round 11
// 504.683 us; speedup vs baseline: 1.2201x; 1.1255x over previous
//
#include <hip/hip_runtime.h>
#include <hip/hip_bf16.h>

#define NP1 50176      // 224*224
#define NP2 12544      // 112*112
#define NPP 12996      // 114*114 zero-padded map

typedef __attribute__((ext_vector_type(8))) short short8;   // 8 bf16 = 4 VGPRs
typedef __attribute__((ext_vector_type(4))) float f32x4;

__device__ __forceinline__ unsigned short f2bu(float f){
  __hip_bfloat16 h = __float2bfloat16(f);
  return *reinterpret_cast<unsigned short*>(&h);
}
__device__ __forceinline__ float blo(unsigned u){ union{unsigned q; float f;} x; x.q = u<<16; return x.f; }
__device__ __forceinline__ float bhi(unsigned u){ union{unsigned q; float f;} x; x.q = u & 0xffff0000u; return x.f; }

// ---- workspace layout (float slots) ----
#define S_SUM1   0          // 128
#define S_SUM2   128        // 512
#define S_STATS1 640        // 128
#define S_STATS2 768        // 512
#define S_W2T    1280       // 576*256 = 147456 fp32
#define S_WOFF2  148736     // 2304*32 = 73728 fp32 (k = n*256+c order)
#define S_W4F    222464     // 589824 bf16 -> 294912 slots (frag-ready [kt][oc][kk], k = n*256+c)
#define S_OFFB   517376     // 2*18*112*112 = 451584 fp32 (NCHW)
#define S_PPAD   968960     // 2*64*114*114 = 1663488 fp32 (NCHW padded)
#define S_HPAD   2632448    // 2*114*114*256 = 6653952 fp32 (NHWC padded)
#define S_PBUF   9286400    // 9*451584 = 4064256 fp32 (per-tap partials)
#define S_HPADH  13350656   // 6653952 bf16 -> 3326976 slots (NHWC bf16 copy for deform gather)
#define WS_NEED_FLOATS 16677632ull
#define WS_NEED_BYTES  (WS_NEED_FLOATS*4ull)   // 66.7 MB (ws ~256MB per R7 fill evidence)

// ---------- weight prep ----------
__global__ void k_w2T(const float* __restrict__ w2, float* __restrict__ w2T){
  int idx = blockIdx.x*256+threadIdx.x;  int kk = idx>>8, oc = idx&255;   // k = c*9+n
  w2T[idx] = w2[oc*576 + kk];
}
// w4 frag-ready bf16: w4f[kt*8192 + oc*32 + kk] = w4[oc][c][n], k = kt*32+kk = n*256+c
__global__ void k_w4f(const float* __restrict__ w4, unsigned short* __restrict__ w4f){
  int idx = blockIdx.x*256+threadIdx.x;        // 589824
  int kt = idx/8192; int r = idx - kt*8192;
  int oc = r>>5, kk = r&31;
  int k = kt*32 + kk; int n = k>>8, c = k&255;
  w4f[idx] = f2bu(w4[oc*2304 + c*9 + n]);
}
// woff2[k][oc], k = n*256+c, oc padded to 32
__global__ void k_woff2(const float* __restrict__ woff, float* __restrict__ woff2){
  int idx = blockIdx.x*256+threadIdx.x;        // 73728
  int k = idx>>5, oc = idx&31;
  int n = k>>8, c = k&255;
  woff2[idx] = (oc<18) ? woff[oc*2304 + c*9 + n] : 0.f;
}

// ---- conv1+bias+ReLU + 2x2 avgpool, LDS x-tile; BN1 partial stats ----
__global__ __launch_bounds__(256) void k_conv1pool(
    const float* __restrict__ x, const float* __restrict__ w1, const float* __restrict__ b1,
    float* __restrict__ ppad, float* __restrict__ sum1){
  __shared__ float xs[3*34*34];         // 13872 B
  int bid = blockIdx.x;                 // 6272 = 2*64*49
  int tile = bid % 49; int oc = (bid/49) & 63; int b = bid/(49*64);
  int tu = tile/7, tv = tile - 7*(tile/7);
  int tid = threadIdx.x;
  int in0 = tu*32 - 1, jn0 = tv*32 - 1;
  for(int t=tid; t<3468; t+=256){
    int c = t/1156; int r2 = t - c*1156; int rr = r2/34; int cc = r2 - rr*34;
    int ii = in0+rr, jj = jn0+cc;
    xs[t] = (ii>=0 && ii<224 && jj>=0 && jj<224) ? x[(size_t)(b*3+c)*NP1 + ii*224+jj] : 0.f;
  }
  float w[27];
  #pragma unroll
  for(int t=0;t<27;t++) w[t] = w1[oc*27+t];
  float bia = b1[oc];
  __syncthreads();
  int u = tid>>4, v = tid&15;           // local pooled coords
  float s1=0.f, s2=0.f, pl=0.f;
  #pragma unroll
  for(int dy=0;dy<2;dy++){
    #pragma unroll
    for(int dx=0;dx<2;dx++){
      float acc = bia;
      #pragma unroll
      for(int c=0;c<3;c++)
        #pragma unroll
        for(int kh=0;kh<3;kh++)
          #pragma unroll
          for(int kw=0;kw<3;kw++)
            acc += xs[c*1156 + (2*u+dy+kh)*34 + (2*v+dx+kw)] * w[c*9+kh*3+kw];
      acc = fmaxf(acc, 0.f);            // relu BEFORE BN
      pl += acc; s1 += acc; s2 += acc*acc;
    }
  }
  int U = tu*16+u, V = tv*16+v;
  ppad[(size_t)(b*64+oc)*NPP + (U+1)*114 + (V+1)] = 0.25f*pl;
  __shared__ float r1[256], r2[256];
  r1[tid]=s1; r2[tid]=s2; __syncthreads();
  for(int o=128;o>0;o>>=1){
    if(tid<o){ r1[tid]+=r1[tid+o]; r2[tid]+=r2[tid+o]; }
    __syncthreads();
  }
  if(tid==0){ atomicAdd(&sum1[oc], r1[0]); atomicAdd(&sum1[64+oc], r2[0]); }
}

__global__ void k_fin1(const float* __restrict__ sum1, const float* __restrict__ g1,
                       const float* __restrict__ be1, float* __restrict__ stats1){
  int ch = threadIdx.x;                 // 64
  float n = 2.f*(float)NP1;
  float mean = sum1[ch]/n;
  float var  = sum1[64+ch]/n - mean*mean;
  float sc = g1[ch]/sqrtf(var + 1e-5f);
  stats1[ch]    = sc;
  stats1[64+ch] = be1[ch] - mean*sc;
}

// ---- in-place BN1 affine on ppad interior; zero border ----
__global__ void k_affine1(float* __restrict__ ppad, const float* __restrict__ stats1){
  int idx = blockIdx.x*256+threadIdx.x;    // 1663488
  int yp = idx % 114; int t = idx/114; int xp = t % 114; t /= 114;
  int c = t & 63;
  bool in = (xp>=1 && xp<=112 && yp>=1 && yp<=112);
  ppad[idx] = in ? (stats1[c]*ppad[idx] + stats1[64+c]) : 0.f;
}

// ---- conv2 GEMM: M=25088,N=256,K=576; bias+relu RAW -> hpad NHWC interior ----
__global__ __launch_bounds__(256) void k_conv2(const float* __restrict__ ppad,
        const float* __restrict__ w2T, const float* __restrict__ b2, float* __restrict__ hpad){
  __shared__ float smem[9216];          // Alds[0,1024) | Blds[1024,9216); tb reuses [0,8224)
  float* Alds = smem; float* Blds = smem+1024; float* tb = smem;
  const int tid = threadIdx.x;
  const int mbase = blockIdx.x*32;
  const int b = mbase/NP2; const int ijbase = mbase - b*NP2;
  const int oc0 = (tid & 31)*8;
  const int p0  = (tid >> 5)*4;
  const float* pb = ppad + (size_t)b*64*NPP;
  float acc[4][8] = {};
  for(int k0=0;k0<576;k0+=32){
    __syncthreads();
    { const float4* src = (const float4*)(w2T + k0*256);
      float4* dst = (float4*)Blds;
      #pragma unroll
      for(int r=0;r<8;r++) dst[r*256+tid] = src[r*256+tid]; }
    #pragma unroll
    for(int r=0;r<4;r++){
      int e = r*256+tid;
      int kk = e>>5, p = e&31;
      int k = k0+kk; int c = k/9; int n = k - 9*c;
      int ij = ijbase+p; int i = ij/112, j = ij - i*112;
      Alds[kk*32+p] = pb[(c*114 + i + n/3)*114 + j + (n%3)];
    }
    __syncthreads();
    #pragma unroll
    for(int kk=0;kk<32;kk++){
      float a0=Alds[kk*32+p0+0], a1=Alds[kk*32+p0+1], a2=Alds[kk*32+p0+2], a3=Alds[kk*32+p0+3];
      const float* bp = &Blds[kk*256+oc0];
      #pragma unroll
      for(int o=0;o<8;o++){
        float bv = bp[o];
        acc[0][o]=fmaf(a0,bv,acc[0][o]); acc[1][o]=fmaf(a1,bv,acc[1][o]);
        acc[2][o]=fmaf(a2,bv,acc[2][o]); acc[3][o]=fmaf(a3,bv,acc[3][o]);
      }
    }
  }
  __syncthreads();
  #pragma unroll
  for(int p=0;p<4;p++)
    #pragma unroll
    for(int o=0;o<8;o++) tb[(p0+p)*257 + oc0+o] = acc[p][o];
  __syncthreads();
  #pragma unroll
  for(int it=0; it<8; it++){
    int id = it*256 + tid;
    int px = id>>6, oc4 = id&63;
    int ij = ijbase+px; int i = ij/112, j = ij - i*112;
    int pp = (i+1)*114 + (j+1);
    float4 v;
    v.x = fmaxf(tb[px*257 + oc4*4+0] + b2[oc4*4+0], 0.f);
    v.y = fmaxf(tb[px*257 + oc4*4+1] + b2[oc4*4+1], 0.f);
    v.z = fmaxf(tb[px*257 + oc4*4+2] + b2[oc4*4+2], 0.f);
    v.w = fmaxf(tb[px*257 + oc4*4+3] + b2[oc4*4+3], 0.f);
    *(float4*)&hpad[((size_t)b*NPP + pp)*256 + oc4*4] = v;   // raw (pre-BN2)
  }
}

// ---- BN2 stats over hpad NHWC interior (thread = channel, coalesced) ----
__global__ __launch_bounds__(256) void k_bnstats2(const float* __restrict__ hpad,
                                                  float* __restrict__ sum2){
  int c = threadIdx.x;
  int q0 = blockIdx.x*98;               // 256 blocks * 98 px = 25088
  float s1=0.f, s2=0.f;
  for(int qi=0; qi<98; qi++){
    int q = q0+qi; int b = q/NP2; int pix = q - b*NP2;
    int pp = (pix/112 + 1)*114 + (pix%112) + 1;
    float v = hpad[((size_t)b*NPP + pp)*256 + c];
    s1 += v; s2 += v*v;
  }
  atomicAdd(&sum2[c], s1); atomicAdd(&sum2[256+c], s2);
}

__global__ void k_fin2(const float* __restrict__ sum2, const float* __restrict__ g2,
                       const float* __restrict__ be2, float* __restrict__ stats2){
  int ch = threadIdx.x;                 // 256
  float n = 2.f*(float)NP2;
  float mean = sum2[ch]/n;
  float var  = sum2[256+ch]/n - mean*mean;
  float sc = g2[ch]/sqrtf(var + 1e-5f);
  stats2[ch]     = sc;
  stats2[256+ch] = be2[ch] - mean*sc;
}

// ---- in-place BN2 affine on hpad NHWC interior; zero border; also emit bf16 copy ----
__global__ void k_affine2(float* __restrict__ hpad, const float* __restrict__ stats2,
                          unsigned short* __restrict__ hpadh){
  int idx = blockIdx.x*256+threadIdx.x;    // 6653952
  int c = idx & 255; int pi = idx >> 8;
  int pp = pi % NPP;
  int row = pp/114, col = pp - row*114;
  bool in = (row>=1 && row<=112 && col>=1 && col<=112);
  float v = in ? (stats2[c]*hpad[idx] + stats2[256+c]) : 0.f;
  hpad[idx]  = v;          // fp32 for convoff (offset numerics must stay fp32)
  hpadh[idx] = f2bu(v);    // bf16 for deform gather
}

// ---- offset conv, SPLIT-K over 9 taps, XCD-swizzled: grid 3528 = 8 xcd * 441 ----
__global__ __launch_bounds__(256) void k_convoff_split(const float* __restrict__ hpad,
        const float* __restrict__ woff2, float* __restrict__ pbuf){
  __shared__ float Alds[32*65];         // [kk][p] stride 65
  __shared__ float Blds[1024];          // [kk][oc]
  const int tid = threadIdx.x;
  const int xcd = blockIdx.x & 7;
  const int r   = blockIdx.x >> 3;      // 0..440 = 9 taps * 49 strips
  const int n   = r/49;                 // tap
  const int mt  = xcd*49 + (r - n*49);  // strip 0..391
  const int mbase = mt*64;
  const int b = mbase/NP2; const int ijbase = mbase - b*NP2;
  const int oc = tid & 31; const int p0 = (tid>>5)*8;
  const float* hb = hpad + (size_t)b*NPP*256;
  float acc[8] = {};
  for(int kt=0; kt<8; kt++){            // K-chunk: c = kt*32 .. +31 within tap n
    int c0 = kt*32;
    __syncthreads();
    ((float4*)Blds)[tid] = ((const float4*)(woff2 + ((size_t)n*256 + c0)*32))[tid];
    #pragma unroll
    for(int it=0; it<2; it++){
      int id = it*256+tid;
      int p = id>>3, kq = id&7;          // 64 px x 8 c-quads
      int ij = ijbase+p; int i = ij/112, j = ij - i*112;
      int pp = (i + n/3)*114 + j + (n%3);
      float4 v = *(const float4*)(hb + (size_t)pp*256 + c0 + kq*4);
      Alds[(kq*4+0)*65+p] = v.x;
      Alds[(kq*4+1)*65+p] = v.y;
      Alds[(kq*4+2)*65+p] = v.z;
      Alds[(kq*4+3)*65+p] = v.w;
    }
    __syncthreads();
    #pragma unroll
    for(int kk=0;kk<32;kk++){
      float bv = Blds[kk*32+oc];
      const float* ap = &Alds[kk*65+p0];
      #pragma unroll
      for(int i2=0;i2<8;i2++) acc[i2] = fmaf(ap[i2], bv, acc[i2]);
    }
  }
  if(oc<18){
    #pragma unroll
    for(int p=0;p<8;p++){
      int ij = ijbase+p0+p;
      pbuf[(size_t)n*451584 + ((size_t)(b*18+oc))*NP2 + ij] = acc[p];
    }
  }
}

// ---- reduce the 9 per-tap partials (deterministic order) + bias ----
__global__ void k_offred(const float* __restrict__ pbuf, const float* __restrict__ boff,
                         float* __restrict__ offb){
  int idx = blockIdx.x*256+threadIdx.x;    // 451584
  int oc = (idx/NP2) % 18;
  float s = boff[oc];
  #pragma unroll
  for(int n=0;n<9;n++) s += pbuf[(size_t)n*451584 + idx];
  offb[idx] = s;
}

// ---- deformable conv: MFMA bf16, M-tile 64, bf16 gather, XCD-swizzled grid 392 = 8*49 ----
__global__ __launch_bounds__(256) void k_deform(
    const unsigned short* __restrict__ hpadh,       // NHWC bf16, affine'd, zero border
    const float* __restrict__ offb,                 // NCHW fp32
    const unsigned short* __restrict__ w4f,         // frag-ready bf16 [72][256][32]
    float* __restrict__ out){
  __shared__ int   gidx[64][9][4];
  __shared__ float gwt [64][9][4];
  __shared__ unsigned short afrag[2][64*40];        // px stride 40 shorts (bank-safe)
  const int tid = threadIdx.x;
  const int wave = tid>>6, lane = tid&63;
  // XCD swizzle: same-XCD blocks form a contiguous 28-row strip (bf16 ~1.7MB < 4MB L2)
  const int sidx = (blockIdx.x & 7)*49 + (blockIdx.x >> 3);
  const int pix0 = sidx*64;
  const int b = pix0/NP2, ij0 = pix0 - b*NP2;

  for(int t=tid; t<576; t+=256){
    int p = t/9, n = t - 9*(t/9);
    int ij = ij0+p; int i = ij/112, j = ij - i*112;
    float ox = offb[(size_t)(b*18 + 2*n  )*NP2 + ij];
    float oy = offb[(size_t)(b*18 + 2*n+1)*NP2 + ij];
    float px = (float)(i + n/3) + ox;
    float py = (float)(j + n%3) + oy;
    float fpx = floorf(px), fpy = floorf(py);
    float qltxf = fminf(fmaxf(fpx,     0.f),113.f);
    float qltyf = fminf(fmaxf(fpy,     0.f),113.f);
    float qrbxf = fminf(fmaxf(fpx+1.f, 0.f),113.f);
    float qrbyf = fminf(fmaxf(fpy+1.f, 0.f),113.f);
    int qltx=(int)qltxf, qlty=(int)qltyf, qrbx=(int)qrbxf, qrby=(int)qrbyf;
    bool mx = (px<1.f)||(px>112.f);
    bool my = (py<1.f)||(py>112.f);
    float pxc = fminf(fmaxf(mx?fpx:px, 0.f),113.f);
    float pyc = fminf(fmaxf(my?fpy:py, 0.f),113.f);
    float glt = (1.f+(qltxf-pxc))*(1.f+(qltyf-pyc));
    float grb = (1.f-(qrbxf-pxc))*(1.f-(qrbyf-pyc));
    float glb = (1.f+(qltxf-pxc))*(1.f-(qrbyf-pyc));
    float grt = (1.f-(qrbxf-pxc))*(1.f+(qltyf-pyc));
    gidx[p][n][0]=qltx*114+qlty; gwt[p][n][0]=glt;
    gidx[p][n][1]=qrbx*114+qrby; gwt[p][n][1]=grb;
    gidx[p][n][2]=qltx*114+qrby; gwt[p][n][2]=glb;  // (lt_x, rb_y)
    gidx[p][n][3]=qrbx*114+qlty; gwt[p][n][3]=grt;  // (rb_x, lt_y)
  }

  const int px_g   = tid>>2;            // 0..63
  const int coff_g = (tid&3)*8;         // 8-channel slice of the 32-ch K-tile
  const unsigned short* hb = hpadh + (size_t)b*NPP*256;

  f32x4 acc[4][4] = {};
  __syncthreads();

  // gather kt -> afrag[buf]: 8 bf16 per thread, frag-ready (px-major, stride 40)
  auto GATHER = [&](int kt, int buf){
    int n = kt>>3; int cb = ((kt&7)<<5) + coff_g;
    const int*   gi = gidx[px_g][n];
    const float* gw = gwt[px_g][n];
    f32x4 va = {0.f,0.f,0.f,0.f}, vb = {0.f,0.f,0.f,0.f};
    #pragma unroll
    for(int cr=0;cr<4;cr++){
      const uint4 u = *(const uint4*)(hb + (size_t)gi[cr]*256 + cb);
      float w = gw[cr];
      va.x = fmaf(w, blo(u.x), va.x); va.y = fmaf(w, bhi(u.x), va.y);
      va.z = fmaf(w, blo(u.y), va.z); va.w = fmaf(w, bhi(u.y), va.w);
      vb.x = fmaf(w, blo(u.z), vb.x); vb.y = fmaf(w, bhi(u.z), vb.y);
      vb.z = fmaf(w, blo(u.w), vb.z); vb.w = fmaf(w, bhi(u.w), vb.w);
    }
    uint4 o;
    o.x = (unsigned)f2bu(va.x) | ((unsigned)f2bu(va.y)<<16);
    o.y = (unsigned)f2bu(va.z) | ((unsigned)f2bu(va.w)<<16);
    o.z = (unsigned)f2bu(vb.x) | ((unsigned)f2bu(vb.y)<<16);
    o.w = (unsigned)f2bu(vb.z) | ((unsigned)f2bu(vb.w)<<16);
    *(uint4*)&afrag[buf][px_g*40 + coff_g] = o;
  };

  const int klo = (lane>>4)<<3;         // k-slice within tile
  GATHER(0, 0);
  for(int kt=0; kt<72; kt++){
    __syncthreads();
    if(kt+1 < 72) GATHER(kt+1, (kt+1)&1);
    const unsigned short* ab = afrag[kt&1];
    short8 aF[4];
    #pragma unroll
    for(int mf=0; mf<4; mf++)
      aF[mf] = *(const short8*)&ab[(mf*16 + (lane&15))*40 + klo];
    const unsigned short* wb = w4f + (size_t)kt*8192 + klo;
    #pragma unroll
    for(int nf=0; nf<4; nf++){
      int oc = wave*64 + nf*16 + (lane&15);
      short8 bF = *(const short8*)&wb[oc*32];
      #pragma unroll
      for(int mf=0; mf<4; mf++)
        acc[mf][nf] = __builtin_amdgcn_mfma_f32_16x16x32_bf16(aF[mf], bF, acc[mf][nf], 0,0,0);
    }
  }
  // epilogue: D col=lane&15 (oc), row=(lane>>4)*4+reg (px)
  int row0 = ((lane>>4)<<2);
  int col  = lane&15;
  #pragma unroll
  for(int mf=0; mf<4; mf++)
    #pragma unroll
    for(int nf=0; nf<4; nf++){
      int oc = wave*64 + nf*16 + col;
      size_t ob = (size_t)(b*256+oc)*NP2 + ij0 + mf*16 + row0;
      *(f32x4*)(out + ob) = acc[mf][nf];
    }
}

extern "C" void kernel_launch(void* const* d_in, const int* in_sizes, int n_in,
                              void* d_out, int out_size, void* d_ws, size_t ws_size,
                              hipStream_t stream){
  (void)in_sizes; (void)n_in;
  const float* x    = (const float*)d_in[0];
  const float* w1   = (const float*)d_in[1];
  const float* b1   = (const float*)d_in[2];
  const float* g1   = (const float*)d_in[3];
  const float* be1  = (const float*)d_in[4];
  const float* w2   = (const float*)d_in[5];
  const float* b2   = (const float*)d_in[6];
  const float* g2   = (const float*)d_in[7];
  const float* be2  = (const float*)d_in[8];
  const float* woff = (const float*)d_in[9];
  const float* boff = (const float*)d_in[10];
  const float* w4   = (const float*)d_in[11];
  float* out = (float*)d_out;
  float* ws = (float*)d_ws;

  if(ws_size < WS_NEED_BYTES){
    hipMemsetAsync(d_out, 0, (size_t)out_size*sizeof(float), stream);
    return;
  }

  float* sum1   = ws + S_SUM1;
  float* sum2   = ws + S_SUM2;
  float* stats1 = ws + S_STATS1;
  float* stats2 = ws + S_STATS2;
  float* w2T    = ws + S_W2T;
  float* woff2  = ws + S_WOFF2;
  unsigned short* w4f = (unsigned short*)(ws + S_W4F);
  float* offb   = ws + S_OFFB;
  float* ppad   = ws + S_PPAD;
  float* hpad   = ws + S_HPAD;
  float* pbuf   = ws + S_PBUF;
  unsigned short* hpadh = (unsigned short*)(ws + S_HPADH);

  hipMemsetAsync(sum1, 0, 640*sizeof(float), stream);   // sum1(128) + sum2(512)
  k_w2T          <<<576,   256, 0, stream>>>(w2, w2T);
  k_w4f          <<<2304,  256, 0, stream>>>(w4, w4f);
  k_woff2        <<<288,   256, 0, stream>>>(woff, woff2);
  k_conv1pool    <<<6272,  256, 0, stream>>>(x, w1, b1, ppad, sum1);
  k_fin1         <<<1,     64,  0, stream>>>(sum1, g1, be1, stats1);
  k_affine1      <<<6498,  256, 0, stream>>>(ppad, stats1);
  k_conv2        <<<784,   256, 0, stream>>>(ppad, w2T, b2, hpad);
  k_bnstats2     <<<256,   256, 0, stream>>>(hpad, sum2);
  k_fin2         <<<1,     256, 0, stream>>>(sum2, g2, be2, stats2);
  k_affine2      <<<25992, 256, 0, stream>>>(hpad, stats2, hpadh);
  k_convoff_split<<<3528,  256, 0, stream>>>(hpad, woff2, pbuf);
  k_offred       <<<1764,  256, 0, stream>>>(pbuf, boff, offb);
  k_deform       <<<392,   256, 0, stream>>>(hpadh, offb, w4f, out);
}

// Round 12
// 411.060 us; speedup vs baseline: 1.4979x; 1.2278x over previous
//
#include <hip/hip_runtime.h>
#include <hip/hip_bf16.h>

#define NP1 50176      // 224*224
#define NP2 12544      // 112*112
#define NPP 12996      // 114*114 zero-padded map

typedef __attribute__((ext_vector_type(8))) short short8;   // 8 bf16 = 4 VGPRs
typedef __attribute__((ext_vector_type(4))) float f32x4;

__device__ __forceinline__ unsigned short f2bu(float f){
  __hip_bfloat16 h = __float2bfloat16(f);
  return *reinterpret_cast<unsigned short*>(&h);
}
__device__ __forceinline__ float blo(unsigned u){ union{unsigned q; float f;} x; x.q = u<<16; return x.f; }
__device__ __forceinline__ float bhi(unsigned u){ union{unsigned q; float f;} x; x.q = u & 0xffff0000u; return x.f; }

// ---- workspace layout (float slots) ----
#define S_SUM1   0          // 128
#define S_SUM2   128        // 512
#define S_STATS1 640        // 128
#define S_STATS2 768        // 512
#define S_WOFF2  1280       // 73728 fp32 (k = n*256+c)
#define S_W4F    75008      // 294912 (589824 bf16 frag-ready)
#define S_W2FH   369920     // 73728 (147456 bf16: w2 hi, frag-ready [kt][oc][kk], k=n*64+c)
#define S_W2FL   443648     // 73728 (147456 bf16: w2 lo)
#define S_OFFB   517376     // 451584 fp32 (NCHW)
#define S_PPAD   968960     // 1663488 fp32 (NCHW padded, raw pool)
#define S_PHI    2632448    // 831744 (1663488 bf16 NHWC hi)
#define S_PLO    3464192    // 831744 (1663488 bf16 NHWC lo)
#define S_HPAD   4295936    // 6653952 fp32 (NHWC padded)
#define S_PBUF   10949888   // 4064256 fp32 (per-tap partials)
#define S_HPADH  15014144   // 3326976 (6653952 bf16 NHWC)
#define WS_NEED_FLOATS 18341120ull
#define WS_NEED_BYTES  (WS_NEED_FLOATS*4ull)   // 73.4 MB

// ---------- weight prep ----------
// w4 frag-ready bf16: w4f[kt*8192 + oc*32 + kk] = w4[oc][c][n], k = kt*32+kk = n*256+c
__global__ void k_w4f(const float* __restrict__ w4, unsigned short* __restrict__ w4f){
  int idx = blockIdx.x*256+threadIdx.x;        // 589824
  int kt = idx/8192; int r = idx - kt*8192;
  int oc = r>>5, kk = r&31;
  int k = kt*32 + kk; int n = k>>8, c = k&255;
  w4f[idx] = f2bu(w4[oc*2304 + c*9 + n]);
}
// woff2[k][oc], k = n*256+c, oc padded to 32
__global__ void k_woff2(const float* __restrict__ woff, float* __restrict__ woff2){
  int idx = blockIdx.x*256+threadIdx.x;        // 73728
  int k = idx>>5, oc = idx&31;
  int n = k>>8, c = k&255;
  woff2[idx] = (oc<18) ? woff[oc*2304 + c*9 + n] : 0.f;
}
// w2 hi/lo frag-ready bf16: [kt][oc][kk], kt<18, k = kt*32+kk = n*64+c
__global__ void k_w2f(const float* __restrict__ w2, unsigned short* __restrict__ w2fh,
                      unsigned short* __restrict__ w2fl){
  int idx = blockIdx.x*256+threadIdx.x;        // 147456
  int kt = idx/8192; int r = idx - kt*8192;
  int oc = r>>5, kk = r&31;
  int k = kt*32 + kk; int n = k>>6, c = k&63;
  float wv = w2[oc*576 + c*9 + n];
  unsigned short hi = f2bu(wv);
  w2fh[idx] = hi;
  w2fl[idx] = f2bu(wv - blo(hi));
}

// ---- conv1+bias+ReLU + 2x2 avgpool, LDS x-tile; BN1 partial stats ----
__global__ __launch_bounds__(256) void k_conv1pool(
    const float* __restrict__ x, const float* __restrict__ w1, const float* __restrict__ b1,
    float* __restrict__ ppad, float* __restrict__ sum1){
  __shared__ float xs[3*34*34];         // 13872 B
  int bid = blockIdx.x;                 // 6272 = 2*64*49
  int tile = bid % 49; int oc = (bid/49) & 63; int b = bid/(49*64);
  int tu = tile/7, tv = tile - 7*(tile/7);
  int tid = threadIdx.x;
  int in0 = tu*32 - 1, jn0 = tv*32 - 1;
  for(int t=tid; t<3468; t+=256){
    int c = t/1156; int r2 = t - c*1156; int rr = r2/34; int cc = r2 - rr*34;
    int ii = in0+rr, jj = jn0+cc;
    xs[t] = (ii>=0 && ii<224 && jj>=0 && jj<224) ? x[(size_t)(b*3+c)*NP1 + ii*224+jj] : 0.f;
  }
  float w[27];
  #pragma unroll
  for(int t=0;t<27;t++) w[t] = w1[oc*27+t];
  float bia = b1[oc];
  __syncthreads();
  int u = tid>>4, v = tid&15;           // local pooled coords
  float s1=0.f, s2=0.f, pl=0.f;
  #pragma unroll
  for(int dy=0;dy<2;dy++){
    #pragma unroll
    for(int dx=0;dx<2;dx++){
      float acc = bia;
      #pragma unroll
      for(int c=0;c<3;c++)
        #pragma unroll
        for(int kh=0;kh<3;kh++)
          #pragma unroll
          for(int kw=0;kw<3;kw++)
            acc += xs[c*1156 + (2*u+dy+kh)*34 + (2*v+dx+kw)] * w[c*9+kh*3+kw];
      acc = fmaxf(acc, 0.f);            // relu BEFORE BN
      pl += acc; s1 += acc; s2 += acc*acc;
    }
  }
  int U = tu*16+u, V = tv*16+v;
  ppad[(size_t)(b*64+oc)*NPP + (U+1)*114 + (V+1)] = 0.25f*pl;
  __shared__ float r1[256], r2[256];
  r1[tid]=s1; r2[tid]=s2; __syncthreads();
  for(int o=128;o>0;o>>=1){
    if(tid<o){ r1[tid]+=r1[tid+o]; r2[tid]+=r2[tid+o]; }
    __syncthreads();
  }
  if(tid==0){ atomicAdd(&sum1[oc], r1[0]); atomicAdd(&sum1[64+oc], r2[0]); }
}

__global__ void k_fin1(const float* __restrict__ sum1, const float* __restrict__ g1,
                       const float* __restrict__ be1, float* __restrict__ stats1){
  int ch = threadIdx.x;                 // 64
  float n = 2.f*(float)NP1;
  float mean = sum1[ch]/n;
  float var  = sum1[64+ch]/n - mean*mean;
  float sc = g1[ch]/sqrtf(var + 1e-5f);
  stats1[ch]    = sc;
  stats1[64+ch] = be1[ch] - mean*sc;
}

// ---- BN1 affine + NCHW->NHWC transpose + hi/lo bf16 split; zero border ----
__global__ __launch_bounds__(256) void k_affine1t(const float* __restrict__ ppad,
        const float* __restrict__ stats1,
        unsigned short* __restrict__ phi, unsigned short* __restrict__ plo){
  __shared__ float ls[64*65];
  int bid = blockIdx.x;                 // 408 = 2*204
  int b = bid/204; int pp0 = (bid - b*204)*64;
  int tid = threadIdx.x;
  #pragma unroll
  for(int it=0; it<16; it++){
    int t = it*256 + tid;
    int c = t>>6, q = t&63;
    int pp = pp0 + q;
    float v = 0.f;
    if(pp < NPP){
      int row = pp/114, col = pp - row*114;
      if(row>=1 && row<=112 && col>=1 && col<=112)
        v = stats1[c]*ppad[(size_t)(b*64+c)*NPP + pp] + stats1[64+c];
    }
    ls[c*65+q] = v;
  }
  __syncthreads();
  #pragma unroll
  for(int it=0; it<16; it++){
    int t = it*256 + tid;
    int q = t>>6, cq = t&63;      // wait: need q slow, c fast
    int qq = t/64, c = t%64;      // lanes: c contiguous for fixed qq? tid 0..255: t=it*256+tid
    (void)q; (void)cq;
    int pp = pp0 + qq%64;         // qq in [it*4, it*4+3]
    int qloc = qq & 63;
    pp = pp0 + qloc;
    if(pp < NPP){
      float v = ls[c*65 + qloc];
      unsigned short hi = f2bu(v);
      phi[((size_t)b*NPP + pp)*64 + c] = hi;
      plo[((size_t)b*NPP + pp)*64 + c] = f2bu(v - blo(hi));
    }
  }
}

// ---- conv2: MFMA bf16x2 (error-compensated), M-tile 64, N=256, K=576 (k=n*64+c) ----
__global__ __launch_bounds__(256) void k_conv2(
    const unsigned short* __restrict__ phi, const unsigned short* __restrict__ plo,
    const unsigned short* __restrict__ w2fh, const unsigned short* __restrict__ w2fl,
    const float* __restrict__ b2, float* __restrict__ hpad){
  __shared__ float smemf[8800];   // pp_tbl[576 ints] | af(5120 floats) ∪ tb(8224 floats)
  int*  pp_tbl = (int*)smemf;
  unsigned short* afh0 = (unsigned short*)(smemf + 576);    // 2*64*40 shorts = 2560 floats
  unsigned short* afl0 = (unsigned short*)(smemf + 576 + 2560);
  float* tb = smemf + 576;
  const int tid = threadIdx.x;
  const int wave = tid>>6, lane = tid&63;
  const int sidx = (blockIdx.x & 7)*49 + (blockIdx.x >> 3);  // XCD swizzle, grid 392
  const int pix0 = sidx*64;
  const int b = pix0/NP2, ij0 = pix0 - b*NP2;

  for(int t=tid; t<576; t+=256){
    int p = t/9, n = t - 9*(t/9);
    int ij = ij0+p; int i = ij/112, j = ij - i*112;
    pp_tbl[p*9+n] = (i + n/3)*114 + (j + n%3);
  }
  const int px_g = tid>>2;
  const int coff = (tid&3)*8;
  const unsigned short* ph_b = phi + (size_t)b*NPP*64;
  const unsigned short* pl_b = plo + (size_t)b*NPP*64;

  f32x4 acc[4][4] = {};
  __syncthreads();

  auto STAGE = [&](int kt, int buf){
    int n = kt>>1; int cb = ((kt&1)<<5) + coff;
    int pp = pp_tbl[px_g*9 + n];
    *(uint4*)&afh0[buf*2560 + px_g*40 + coff] = *(const uint4*)(ph_b + (size_t)pp*64 + cb);
    *(uint4*)&afl0[buf*2560 + px_g*40 + coff] = *(const uint4*)(pl_b + (size_t)pp*64 + cb);
  };

  const int klo = (lane>>4)<<3;
  STAGE(0, 0);
  for(int kt=0; kt<18; kt++){
    __syncthreads();
    if(kt+1 < 18) STAGE(kt+1, (kt+1)&1);
    const unsigned short* abh = afh0 + (kt&1)*2560;
    const unsigned short* abl = afl0 + (kt&1)*2560;
    short8 aH[4], aL[4];
    #pragma unroll
    for(int mf=0; mf<4; mf++){
      aH[mf] = *(const short8*)&abh[(mf*16 + (lane&15))*40 + klo];
      aL[mf] = *(const short8*)&abl[(mf*16 + (lane&15))*40 + klo];
    }
    #pragma unroll
    for(int nf=0; nf<4; nf++){
      int oc = wave*64 + nf*16 + (lane&15);
      short8 bH = *(const short8*)&w2fh[(size_t)kt*8192 + oc*32 + klo];
      short8 bL = *(const short8*)&w2fl[(size_t)kt*8192 + oc*32 + klo];
      #pragma unroll
      for(int mf=0; mf<4; mf++){
        acc[mf][nf] = __builtin_amdgcn_mfma_f32_16x16x32_bf16(aH[mf], bH, acc[mf][nf], 0,0,0);
        acc[mf][nf] = __builtin_amdgcn_mfma_f32_16x16x32_bf16(aH[mf], bL, acc[mf][nf], 0,0,0);
        acc[mf][nf] = __builtin_amdgcn_mfma_f32_16x16x32_bf16(aL[mf], bH, acc[mf][nf], 0,0,0);
      }
    }
  }
  // epilogue: two 32-px halves through tb (bias+relu), NHWC float4 stores
  const int row0 = (lane>>4)<<2, col = lane&15;
  for(int half=0; half<2; half++){
    __syncthreads();
    #pragma unroll
    for(int m2=0; m2<2; m2++){
      int mf = half*2 + m2;
      #pragma unroll
      for(int nf=0; nf<4; nf++){
        int oc = wave*64 + nf*16 + col;
        #pragma unroll
        for(int r=0;r<4;r++) tb[(m2*16 + row0 + r)*257 + oc] = acc[mf][nf][r];
      }
    }
    __syncthreads();
    #pragma unroll
    for(int it=0; it<8; it++){
      int id = it*256 + tid;
      int pxl = id>>6, oc4 = id&63;
      int px = half*32 + pxl;
      int ij = ij0+px; int i = ij/112, j = ij - i*112;
      int pp = (i+1)*114 + (j+1);
      float4 v;
      v.x = fmaxf(tb[pxl*257 + oc4*4+0] + b2[oc4*4+0], 0.f);
      v.y = fmaxf(tb[pxl*257 + oc4*4+1] + b2[oc4*4+1], 0.f);
      v.z = fmaxf(tb[pxl*257 + oc4*4+2] + b2[oc4*4+2], 0.f);
      v.w = fmaxf(tb[pxl*257 + oc4*4+3] + b2[oc4*4+3], 0.f);
      *(float4*)&hpad[((size_t)b*NPP + pp)*256 + oc4*4] = v;   // raw (pre-BN2)
    }
  }
}

// ---- BN2 stats over hpad NHWC interior (thread = channel, coalesced) ----
__global__ __launch_bounds__(256) void k_bnstats2(const float* __restrict__ hpad,
                                                  float* __restrict__ sum2){
  int c = threadIdx.x;
  int q0 = blockIdx.x*98;               // 256 blocks * 98 px = 25088
  float s1=0.f, s2=0.f;
  for(int qi=0; qi<98; qi++){
    int q = q0+qi; int b = q/NP2; int pix = q - b*NP2;
    int pp = (pix/112 + 1)*114 + (pix%112) + 1;
    float v = hpad[((size_t)b*NPP + pp)*256 + c];
    s1 += v; s2 += v*v;
  }
  atomicAdd(&sum2[c], s1); atomicAdd(&sum2[256+c], s2);
}

__global__ void k_fin2(const float* __restrict__ sum2, const float* __restrict__ g2,
                       const float* __restrict__ be2, float* __restrict__ stats2){
  int ch = threadIdx.x;                 // 256
  float n = 2.f*(float)NP2;
  float mean = sum2[ch]/n;
  float var  = sum2[256+ch]/n - mean*mean;
  float sc = g2[ch]/sqrtf(var + 1e-5f);
  stats2[ch]     = sc;
  stats2[256+ch] = be2[ch] - mean*sc;
}

// ---- in-place BN2 affine on hpad NHWC interior; zero border; also emit bf16 copy ----
__global__ void k_affine2(float* __restrict__ hpad, const float* __restrict__ stats2,
                          unsigned short* __restrict__ hpadh){
  int idx = blockIdx.x*256+threadIdx.x;    // 6653952
  int c = idx & 255; int pi = idx >> 8;
  int pp = pi % NPP;
  int row = pp/114, col = pp - row*114;
  bool in = (row>=1 && row<=112 && col>=1 && col<=112);
  float v = in ? (stats2[c]*hpad[idx] + stats2[256+c]) : 0.f;
  hpad[idx]  = v;          // fp32 for convoff (offset numerics must stay fp32)
  hpadh[idx] = f2bu(v);    // bf16 for deform gather
}

// ---- offset conv, SPLIT-K over 9 taps, XCD-swizzled: grid 3528 = 8 xcd * 441 ----
__global__ __launch_bounds__(256) void k_convoff_split(const float* __restrict__ hpad,
        const float* __restrict__ woff2, float* __restrict__ pbuf){
  __shared__ float Alds[32*65];         // [kk][p] stride 65
  __shared__ float Blds[1024];          // [kk][oc]
  const int tid = threadIdx.x;
  const int xcd = blockIdx.x & 7;
  const int r   = blockIdx.x >> 3;      // 0..440 = 9 taps * 49 strips
  const int n   = r/49;                 // tap
  const int mt  = xcd*49 + (r - n*49);  // strip 0..391
  const int mbase = mt*64;
  const int b = mbase/NP2; const int ijbase = mbase - b*NP2;
  const int oc = tid & 31; const int p0 = (tid>>5)*8;
  const float* hb = hpad + (size_t)b*NPP*256;
  float acc[8] = {};
  for(int kt=0; kt<8; kt++){            // K-chunk: c = kt*32 .. +31 within tap n
    int c0 = kt*32;
    __syncthreads();
    ((float4*)Blds)[tid] = ((const float4*)(woff2 + ((size_t)n*256 + c0)*32))[tid];
    #pragma unroll
    for(int it=0; it<2; it++){
      int id = it*256+tid;
      int p = id>>3, kq = id&7;          // 64 px x 8 c-quads
      int ij = ijbase+p; int i = ij/112, j = ij - i*112;
      int pp = (i + n/3)*114 + j + (n%3);
      float4 v = *(const float4*)(hb + (size_t)pp*256 + c0 + kq*4);
      Alds[(kq*4+0)*65+p] = v.x;
      Alds[(kq*4+1)*65+p] = v.y;
      Alds[(kq*4+2)*65+p] = v.z;
      Alds[(kq*4+3)*65+p] = v.w;
    }
    __syncthreads();
    #pragma unroll
    for(int kk=0;kk<32;kk++){
      float bv = Blds[kk*32+oc];
      const float* ap = &Alds[kk*65+p0];
      #pragma unroll
      for(int i2=0;i2<8;i2++) acc[i2] = fmaf(ap[i2], bv, acc[i2]);
    }
  }
  if(oc<18){
    #pragma unroll
    for(int p=0;p<8;p++){
      int ij = ijbase+p0+p;
      pbuf[(size_t)n*451584 + ((size_t)(b*18+oc))*NP2 + ij] = acc[p];
    }
  }
}

// ---- reduce the 9 per-tap partials (deterministic order) + bias ----
__global__ void k_offred(const float* __restrict__ pbuf, const float* __restrict__ boff,
                         float* __restrict__ offb){
  int idx = blockIdx.x*256+threadIdx.x;    // 451584
  int oc = (idx/NP2) % 18;
  float s = boff[oc];
  #pragma unroll
  for(int n=0;n<9;n++) s += pbuf[(size_t)n*451584 + idx];
  offb[idx] = s;
}

// ---- deformable conv: MFMA bf16, M-tile 64, bf16 gather, XCD-swizzled grid 392 = 8*49 ----
__global__ __launch_bounds__(256) void k_deform(
    const unsigned short* __restrict__ hpadh,       // NHWC bf16, affine'd, zero border
    const float* __restrict__ offb,                 // NCHW fp32
    const unsigned short* __restrict__ w4f,         // frag-ready bf16 [72][256][32]
    float* __restrict__ out){
  __shared__ int   gidx[64][9][4];
  __shared__ float gwt [64][9][4];
  __shared__ unsigned short afrag[2][64*40];        // px stride 40 shorts (bank-safe)
  const int tid = threadIdx.x;
  const int wave = tid>>6, lane = tid&63;
  const int sidx = (blockIdx.x & 7)*49 + (blockIdx.x >> 3);
  const int pix0 = sidx*64;
  const int b = pix0/NP2, ij0 = pix0 - b*NP2;

  for(int t=tid; t<576; t+=256){
    int p = t/9, n = t - 9*(t/9);
    int ij = ij0+p; int i = ij/112, j = ij - i*112;
    float ox = offb[(size_t)(b*18 + 2*n  )*NP2 + ij];
    float oy = offb[(size_t)(b*18 + 2*n+1)*NP2 + ij];
    float px = (float)(i + n/3) + ox;
    float py = (float)(j + n%3) + oy;
    float fpx = floorf(px), fpy = floorf(py);
    float qltxf = fminf(fmaxf(fpx,     0.f),113.f);
    float qltyf = fminf(fmaxf(fpy,     0.f),113.f);
    float qrbxf = fminf(fmaxf(fpx+1.f, 0.f),113.f);
    float qrbyf = fminf(fmaxf(fpy+1.f, 0.f),113.f);
    int qltx=(int)qltxf, qlty=(int)qltyf, qrbx=(int)qrbxf, qrby=(int)qrbyf;
    bool mx = (px<1.f)||(px>112.f);
    bool my = (py<1.f)||(py>112.f);
    float pxc = fminf(fmaxf(mx?fpx:px, 0.f),113.f);
    float pyc = fminf(fmaxf(my?fpy:py, 0.f),113.f);
    float glt = (1.f+(qltxf-pxc))*(1.f+(qltyf-pyc));
    float grb = (1.f-(qrbxf-pxc))*(1.f-(qrbyf-pyc));
    float glb = (1.f+(qltxf-pxc))*(1.f-(qrbyf-pyc));
    float grt = (1.f-(qrbxf-pxc))*(1.f+(qltyf-pyc));
    gidx[p][n][0]=qltx*114+qlty; gwt[p][n][0]=glt;
    gidx[p][n][1]=qrbx*114+qrby; gwt[p][n][1]=grb;
    gidx[p][n][2]=qltx*114+qrby; gwt[p][n][2]=glb;  // (lt_x, rb_y)
    gidx[p][n][3]=qrbx*114+qlty; gwt[p][n][3]=grt;  // (rb_x, lt_y)
  }

  const int px_g   = tid>>2;            // 0..63
  const int coff_g = (tid&3)*8;         // 8-channel slice of the 32-ch K-tile
  const unsigned short* hb = hpadh + (size_t)b*NPP*256;

  f32x4 acc[4][4] = {};
  __syncthreads();

  auto GATHER = [&](int kt, int buf){
    int n = kt>>3; int cb = ((kt&7)<<5) + coff_g;
    const int*   gi = gidx[px_g][n];
    const float* gw = gwt[px_g][n];
    f32x4 va = {0.f,0.f,0.f,0.f}, vb = {0.f,0.f,0.f,0.f};
    #pragma unroll
    for(int cr=0;cr<4;cr++){
      const uint4 u = *(const uint4*)(hb + (size_t)gi[cr]*256 + cb);
      float w = gw[cr];
      va.x = fmaf(w, blo(u.x), va.x); va.y = fmaf(w, bhi(u.x), va.y);
      va.z = fmaf(w, blo(u.y), va.z); va.w = fmaf(w, bhi(u.y), va.w);
      vb.x = fmaf(w, blo(u.z), vb.x); vb.y = fmaf(w, bhi(u.z), vb.y);
      vb.z = fmaf(w, blo(u.w), vb.z); vb.w = fmaf(w, bhi(u.w), vb.w);
    }
    uint4 o;
    o.x = (unsigned)f2bu(va.x) | ((unsigned)f2bu(va.y)<<16);
    o.y = (unsigned)f2bu(va.z) | ((unsigned)f2bu(va.w)<<16);
    o.z = (unsigned)f2bu(vb.x) | ((unsigned)f2bu(vb.y)<<16);
    o.w = (unsigned)f2bu(vb.z) | ((unsigned)f2bu(vb.w)<<16);
    *(uint4*)&afrag[buf][px_g*40 + coff_g] = o;
  };

  const int klo = (lane>>4)<<3;         // k-slice within tile
  GATHER(0, 0);
  for(int kt=0; kt<72; kt++){
    __syncthreads();
    if(kt+1 < 72) GATHER(kt+1, (kt+1)&1);
    const unsigned short* ab = afrag[kt&1];
    short8 aF[4];
    #pragma unroll
    for(int mf=0; mf<4; mf++)
      aF[mf] = *(const short8*)&ab[(mf*16 + (lane&15))*40 + klo];
    const unsigned short* wb = w4f + (size_t)kt*8192 + klo;
    #pragma unroll
    for(int nf=0; nf<4; nf++){
      int oc = wave*64 + nf*16 + (lane&15);
      short8 bF = *(const short8*)&wb[oc*32];
      #pragma unroll
      for(int mf=0; mf<4; mf++)
        acc[mf][nf] = __builtin_amdgcn_mfma_f32_16x16x32_bf16(aF[mf], bF, acc[mf][nf], 0,0,0);
    }
  }
  int row0 = ((lane>>4)<<2);
  int col  = lane&15;
  #pragma unroll
  for(int mf=0; mf<4; mf++)
    #pragma unroll
    for(int nf=0; nf<4; nf++){
      int oc = wave*64 + nf*16 + col;
      size_t ob = (size_t)(b*256+oc)*NP2 + ij0 + mf*16 + row0;
      *(f32x4*)(out + ob) = acc[mf][nf];
    }
}

extern "C" void kernel_launch(void* const* d_in, const int* in_sizes, int n_in,
                              void* d_out, int out_size, void* d_ws, size_t ws_size,
                              hipStream_t stream){
  (void)in_sizes; (void)n_in;
  const float* x    = (const float*)d_in[0];
  const float* w1   = (const float*)d_in[1];
  const float* b1   = (const float*)d_in[2];
  const float* g1   = (const float*)d_in[3];
  const float* be1  = (const float*)d_in[4];
  const float* w2   = (const float*)d_in[5];
  const float* b2   = (const float*)d_in[6];
  const float* g2   = (const float*)d_in[7];
  const float* be2  = (const float*)d_in[8];
  const float* woff = (const float*)d_in[9];
  const float* boff = (const float*)d_in[10];
  const float* w4   = (const float*)d_in[11];
  float* out = (float*)d_out;
  float* ws = (float*)d_ws;

  if(ws_size < WS_NEED_BYTES){
    hipMemsetAsync(d_out, 0, (size_t)out_size*sizeof(float), stream);
    return;
  }

  float* sum1   = ws + S_SUM1;
  float* sum2   = ws + S_SUM2;
  float* stats1 = ws + S_STATS1;
  float* stats2 = ws + S_STATS2;
  float* woff2  = ws + S_WOFF2;
  unsigned short* w4f  = (unsigned short*)(ws + S_W4F);
  unsigned short* w2fh = (unsigned short*)(ws + S_W2FH);
  unsigned short* w2fl = (unsigned short*)(ws + S_W2FL);
  float* offb   = ws + S_OFFB;
  float* ppad   = ws + S_PPAD;
  unsigned short* phi = (unsigned short*)(ws + S_PHI);
  unsigned short* plo = (unsigned short*)(ws + S_PLO);
  float* hpad   = ws + S_HPAD;
  float* pbuf   = ws + S_PBUF;
  unsigned short* hpadh = (unsigned short*)(ws + S_HPADH);

  hipMemsetAsync(sum1, 0, 640*sizeof(float), stream);   // sum1(128) + sum2(512)
  k_w4f          <<<2304,  256, 0, stream>>>(w4, w4f);
  k_woff2        <<<288,   256, 0, stream>>>(woff, woff2);
  k_w2f          <<<576,   256, 0, stream>>>(w2, w2fh, w2fl);
  k_conv1pool    <<<6272,  256, 0, stream>>>(x, w1, b1, ppad, sum1);
  k_fin1         <<<1,     64,  0, stream>>>(sum1, g1, be1, stats1);
  k_affine1t     <<<408,   256, 0, stream>>>(ppad, stats1, phi, plo);
  k_conv2        <<<392,   256, 0, stream>>>(phi, plo, w2fh, w2fl, b2, hpad);
  k_bnstats2     <<<256,   256, 0, stream>>>(hpad, sum2);
  k_fin2         <<<1,     256, 0, stream>>>(sum2, g2, be2, stats2);
  k_affine2      <<<25992, 256, 0, stream>>>(hpad, stats2, hpadh);
  k_convoff_split<<<3528,  256, 0, stream>>>(hpad, woff2, pbuf);
  k_offred       <<<1764,  256, 0, stream>>>(pbuf, boff, offb);
  k_deform       <<<392,   256, 0, stream>>>(hpadh, offb, w4f, out);
}